// Round 6
// baseline (419.455 us; speedup 1.0000x reference)
//
#include <hip/hip_runtime.h>
#include <hip/hip_bf16.h>
#include <math.h>

// Problem constants
#define BB 2
#define SS 2048
#define EE 1024
#define HH 16
#define HD 64
#define FFF 4096
#define MROWS (BB * SS)        // 4096
#define EPS_F 1.1920929e-7f
#define NQKV 1152              // 1024 q + 64 k + 64 v

typedef __hip_bfloat16 bf16;
typedef __attribute__((ext_vector_type(8))) short short8;
typedef __attribute__((ext_vector_type(4))) short short4v;
typedef __attribute__((ext_vector_type(4))) float floatx4;

typedef const __attribute__((address_space(1))) void* gas_t;
typedef __attribute__((address_space(3))) void* las_t;

// scheduling primitives for the 8-phase FFN kernel
#define BAR __builtin_amdgcn_s_barrier()
#define WLG do { asm volatile("s_waitcnt lgkmcnt(0)" ::: "memory"); \
                 __builtin_amdgcn_sched_barrier(0); } while (0)
#define VMC(N) asm volatile("s_waitcnt vmcnt(" #N ")" ::: "memory")

// ---------------------------------------------------------------------------
// RMSNorm: fp32 in, bf16 out. float4-vectorized (cols == 1024 == 256*4).
// ---------------------------------------------------------------------------
__global__ __launch_bounds__(256) void rmsnorm_kernel(const float* __restrict__ x,
                                                      const float* __restrict__ g,
                                                      bf16* __restrict__ out,
                                                      int cols) {
    int row = blockIdx.x, tid = threadIdx.x;
    const float4* xr = (const float4*)(x + (size_t)row * cols);
    float4 v = xr[tid];
    float ss = v.x * v.x + v.y * v.y + v.z * v.z + v.w * v.w;
    for (int off = 32; off > 0; off >>= 1) ss += __shfl_xor(ss, off, 64);
    __shared__ float red[4];
    int wave = tid >> 6;
    if ((tid & 63) == 0) red[wave] = ss;
    __syncthreads();
    float tot = red[0] + red[1] + red[2] + red[3];
    float rs = rsqrtf(tot / (float)cols + EPS_F);
    float4 gv = ((const float4*)g)[tid];
    short4v o;
    {
        bf16 b0 = __float2bfloat16(v.x * rs * gv.x);
        bf16 b1 = __float2bfloat16(v.y * rs * gv.y);
        bf16 b2 = __float2bfloat16(v.z * rs * gv.z);
        bf16 b3 = __float2bfloat16(v.w * rs * gv.w);
        o[0] = *(short*)&b0; o[1] = *(short*)&b1;
        o[2] = *(short*)&b2; o[3] = *(short*)&b3;
    }
    *(short4v*)(out + (size_t)row * cols + tid * 4) = o;
}

// ---------------------------------------------------------------------------
// 32x32 transpose+cast tile body (shared by the two fused weight-prep kernels)
// ---------------------------------------------------------------------------
__device__ __forceinline__ void transpose_tile32(const float* __restrict__ W,
                                                 bf16* __restrict__ Wt,
                                                 int K, int N, int bx, int by,
                                                 int tid, float (*t)[33]) {
    int n0 = bx * 32, k0 = by * 32;
    int tx = tid & 31, ty = tid >> 5;   // ty 0..7
#pragma unroll
    for (int i = 0; i < 4; ++i) {
        int kk = ty + i * 8;
        t[kk][tx] = W[(size_t)(k0 + kk) * N + n0 + tx];
    }
    __syncthreads();
#pragma unroll
    for (int i = 0; i < 4; ++i) {
        int nn = ty + i * 8;
        Wt[(size_t)(n0 + nn) * K + k0 + tx] = __float2bfloat16(t[tx][nn]);
    }
}

// ---------------------------------------------------------------------------
// Fused attention-side prep (1 launch):
//   wq/wk/wv/wo transposes + [bq|bk|bv] pack + RoPE cos/sin tables.
// Block ranges: [0,1024) wq | [1024,1088) wk | [1088,1152) wv |
//               [1152,2176) wo | [2176,2432) rope table | [2432,2437) pack.
// ---------------------------------------------------------------------------
__global__ __launch_bounds__(256) void prep_weights_kernel(
        const float* __restrict__ wq, const float* __restrict__ wk,
        const float* __restrict__ wv, const float* __restrict__ wo,
        const float* __restrict__ bq, const float* __restrict__ bk,
        const float* __restrict__ bv,
        bf16* __restrict__ wqkvT, bf16* __restrict__ woT,
        float* __restrict__ bqkv, float* __restrict__ ct, float* __restrict__ st) {
    __shared__ float t[32][33];
    int bid = blockIdx.x, tid = threadIdx.x;
    if (bid < 1024) {
        transpose_tile32(wq, wqkvT, EE, EE, bid & 31, bid >> 5, tid, t);
    } else if (bid < 1088) {
        int b2 = bid - 1024;
        transpose_tile32(wk, wqkvT + (size_t)1024 * EE, EE, HD, b2 & 1, b2 >> 1, tid, t);
    } else if (bid < 1152) {
        int b2 = bid - 1088;
        transpose_tile32(wv, wqkvT + (size_t)1088 * EE, EE, HD, b2 & 1, b2 >> 1, tid, t);
    } else if (bid < 2176) {
        int b2 = bid - 1152;
        transpose_tile32(wo, woT, EE, EE, b2 & 31, b2 >> 5, tid, t);
    } else if (bid < 2432) {
        int idx = (bid - 2176) * 256 + tid;       // SS*32 = 65536 entries
        int i = idx & 31, s = idx >> 5;
        float inv = powf(10000.0f, -(float)i / 32.0f);
        float ang = (float)s * inv;
        ct[idx] = cosf(ang);
        st[idx] = sinf(ang);
    } else {
        int tt = (bid - 2432) * 256 + tid;
        if (tt < NQKV) {
            float v;
            if (tt < 1024)      v = bq[tt];
            else if (tt < 1088) v = bk[tt - 1024];
            else                v = bv[tt - 1088];
            bqkv[tt] = v;
        }
    }
}

// ---------------------------------------------------------------------------
// Fused FFN weight prep (1 launch): wg/wu/wd transposes.
// [0,4096) wg | [4096,8192) wu | [8192,12288) wd.
// ---------------------------------------------------------------------------
__global__ __launch_bounds__(256) void ffn_weights_kernel(
        const float* __restrict__ wg, const float* __restrict__ wu,
        const float* __restrict__ wd,
        bf16* __restrict__ wgT, bf16* __restrict__ wuT, bf16* __restrict__ wdT) {
    __shared__ float t[32][33];
    int bid = blockIdx.x, tid = threadIdx.x;
    if (bid < 4096) {
        transpose_tile32(wg, wgT, EE, FFF, bid & 127, bid >> 7, tid, t);
    } else if (bid < 8192) {
        int b2 = bid - 4096;
        transpose_tile32(wu, wuT, EE, FFF, b2 & 127, b2 >> 7, tid, t);
    } else {
        int b2 = bid - 8192;
        transpose_tile32(wd, wdT, FFF, EE, b2 & 31, b2 >> 5, tid, t);
    }
}

// ---------------------------------------------------------------------------
// QKV GEMM, split-K=2 (blockIdx.z): each half writes pure fp32 partials
// (no bias/rope — those move to qkv_combine). 576 blocks (was 288 = 1.1/CU):
// the 2-phase stage->drain->barrier chain needs TLP (round-1/2 lesson).
// ---------------------------------------------------------------------------
#define GK 64

__global__ __launch_bounds__(256) void gemm_qkv_kernel(
        const bf16* __restrict__ A, const bf16* __restrict__ Bt,
        float* __restrict__ p0, float* __restrict__ p1, int K) {
    __shared__ short As[128 * GK];
    __shared__ short Bs[128 * GK];
    int tid = threadIdx.x;
    int wave = tid >> 6, lane = tid & 63;
    int wm = (wave >> 1) * 64, wn = (wave & 1) * 64;
    int row0 = blockIdx.y * 128, col0 = blockIdx.x * 128;
    int lr = lane & 15, lq = lane >> 4;
    int kh = blockIdx.z;
    int kbeg = kh * (K >> 1), kend = kbeg + (K >> 1);

    int srow = wave * 32 + (lane >> 3);
    int scol = (lane & 7) * 8;
    const bf16* Abase = A + (size_t)(row0 + srow) * K + scol;
    const bf16* Bbase = Bt + (size_t)(col0 + srow) * K + scol;

    floatx4 acc[4][4];
#pragma unroll
    for (int mi = 0; mi < 4; ++mi)
#pragma unroll
        for (int ni = 0; ni < 4; ++ni)
            acc[mi][ni] = (floatx4){0.f, 0.f, 0.f, 0.f};

    for (int k0 = kbeg; k0 < kend; k0 += GK) {
        __syncthreads();
#pragma unroll
        for (int c = 0; c < 4; ++c) {
            __builtin_amdgcn_global_load_lds(
                (gas_t)(Abase + (size_t)(c * 8) * K + k0),
                (las_t)&As[(wave * 32 + c * 8) * GK], 16, 0, 0);
            __builtin_amdgcn_global_load_lds(
                (gas_t)(Bbase + (size_t)(c * 8) * K + k0),
                (las_t)&Bs[(wave * 32 + c * 8) * GK], 16, 0, 0);
        }
        __syncthreads();
#pragma unroll
        for (int ks = 0; ks < GK; ks += 32) {
            short8 af[4], bfr[4];
#pragma unroll
            for (int mi = 0; mi < 4; ++mi)
                af[mi] = *(const short8*)&As[(wm + mi * 16 + lr) * GK + ks + lq * 8];
#pragma unroll
            for (int ni = 0; ni < 4; ++ni)
                bfr[ni] = *(const short8*)&Bs[(wn + ni * 16 + lr) * GK + ks + lq * 8];
#pragma unroll
            for (int mi = 0; mi < 4; ++mi)
#pragma unroll
                for (int ni = 0; ni < 4; ++ni)
                    acc[mi][ni] = __builtin_amdgcn_mfma_f32_16x16x32_bf16(
                        af[mi], bfr[ni], acc[mi][ni], 0, 0, 0);
        }
    }

    float* __restrict__ P = kh ? p1 : p0;
#pragma unroll
    for (int mi = 0; mi < 4; ++mi)
#pragma unroll
        for (int ni = 0; ni < 4; ++ni) {
            int gc = col0 + wn + ni * 16 + lr;
#pragma unroll
            for (int r = 0; r < 4; ++r) {
                int gr = row0 + wm + mi * 16 + lq * 4 + r;
                P[(size_t)gr * NQKV + gc] = acc[mi][ni][r];
            }
        }
}

// ---------------------------------------------------------------------------
// qkv combine: t = p0 + p1 + bias, then RoPE for q (x0.125) and k, cast v.
// 192 threads (3 waves); grid (3, MROWS); j in [0,576):
//   [0,512) q rotation pairs | [512,544) k pairs | [544,576) v (2 elems each).
// ---------------------------------------------------------------------------
__global__ __launch_bounds__(192) void qkv_combine_kernel(
        const float* __restrict__ p0, const float* __restrict__ p1,
        const float* __restrict__ bias, const float* __restrict__ ct,
        const float* __restrict__ st, bf16* __restrict__ qout,
        bf16* __restrict__ kout, bf16* __restrict__ vout) {
    int row = blockIdx.y;
    int j = blockIdx.x * 192 + threadIdx.x;
    const float* r0 = p0 + (size_t)row * NQKV;
    const float* r1 = p1 + (size_t)row * NQKV;
    int s = row & (SS - 1);
    if (j < 544) {
        int i, col1;
        if (j < 512) { i = j & 31; col1 = (j >> 5) * 64 + i; }
        else         { i = j - 512; col1 = 1024 + i; }
        int col2 = col1 + 32;
        float t1 = r0[col1] + r1[col1] + bias[col1];
        float t2 = r0[col2] + r1[col2] + bias[col2];
        float c = ct[s * 32 + i], sn = st[s * 32 + i];
        float o1 = t1 * c - t2 * sn;
        float o2 = t1 * sn + t2 * c;
        if (j < 512) {
            qout[(size_t)row * 1024 + col1]      = __float2bfloat16(o1 * 0.125f);
            qout[(size_t)row * 1024 + col1 + 32] = __float2bfloat16(o2 * 0.125f);
        } else {
            kout[(size_t)row * 64 + i]      = __float2bfloat16(o1);
            kout[(size_t)row * 64 + i + 32] = __float2bfloat16(o2);
        }
    } else {
        int i = (j - 544) * 2;
        int col = 1088 + i;
        vout[(size_t)row * 64 + i]     = __float2bfloat16(r0[col] + r1[col] + bias[col]);
        vout[(size_t)row * 64 + i + 1] = __float2bfloat16(r0[col + 1] + r1[col + 1] + bias[col + 1]);
    }
}

// ---------------------------------------------------------------------------
// GEMM 128x64 tiles, split-K=2 (blockIdx.z) for N=1024 outputs (wo, wd):
//   z=0: C = acc(K-half0) + bias + aux   (direct write)
//   z=1: P = acc(K-half1)                (partial; add_inplace joins after)
// Disjoint outputs -> no race; one launch -> halves co-resident (wd: 4/CU).
// ---------------------------------------------------------------------------
__global__ __launch_bounds__(256) void gemm_n64_split_kernel(
        const bf16* __restrict__ A, const bf16* __restrict__ Bt,
        const float* __restrict__ bias, const float* __restrict__ aux,
        float* __restrict__ C, float* __restrict__ P, int N, int K) {
    __shared__ short As[128 * GK];
    __shared__ short Bs[64 * GK];
    int tid = threadIdx.x;
    int wave = tid >> 6, lane = tid & 63;
    int wm = wave * 32;
    int row0 = blockIdx.y * 128, col0 = blockIdx.x * 64;
    int lr = lane & 15, lq = lane >> 4;
    int kh = blockIdx.z;
    int kbeg = kh * (K >> 1), kend = kbeg + (K >> 1);

    int srow = (lane >> 3);
    int scol = (lane & 7) * 8;
    const bf16* Abase = A + (size_t)(row0 + wave * 32 + srow) * K + scol;
    const bf16* Bbase = Bt + (size_t)(col0 + wave * 16 + srow) * K + scol;

    floatx4 acc[2][4];
#pragma unroll
    for (int mi = 0; mi < 2; ++mi)
#pragma unroll
        for (int ni = 0; ni < 4; ++ni)
            acc[mi][ni] = (floatx4){0.f, 0.f, 0.f, 0.f};

    for (int k0 = kbeg; k0 < kend; k0 += GK) {
        __syncthreads();
#pragma unroll
        for (int c = 0; c < 4; ++c)
            __builtin_amdgcn_global_load_lds(
                (gas_t)(Abase + (size_t)(c * 8) * K + k0),
                (las_t)&As[(wave * 32 + c * 8) * GK], 16, 0, 0);
#pragma unroll
        for (int c = 0; c < 2; ++c)
            __builtin_amdgcn_global_load_lds(
                (gas_t)(Bbase + (size_t)(c * 8) * K + k0),
                (las_t)&Bs[(wave * 16 + c * 8) * GK], 16, 0, 0);
        __syncthreads();
#pragma unroll
        for (int ks = 0; ks < GK; ks += 32) {
            short8 af[2], bfr[4];
#pragma unroll
            for (int mi = 0; mi < 2; ++mi)
                af[mi] = *(const short8*)&As[(wm + mi * 16 + lr) * GK + ks + lq * 8];
#pragma unroll
            for (int ni = 0; ni < 4; ++ni)
                bfr[ni] = *(const short8*)&Bs[(ni * 16 + lr) * GK + ks + lq * 8];
#pragma unroll
            for (int mi = 0; mi < 2; ++mi)
#pragma unroll
                for (int ni = 0; ni < 4; ++ni)
                    acc[mi][ni] = __builtin_amdgcn_mfma_f32_16x16x32_bf16(
                        af[mi], bfr[ni], acc[mi][ni], 0, 0, 0);
        }
    }

#pragma unroll
    for (int mi = 0; mi < 2; ++mi) {
#pragma unroll
        for (int ni = 0; ni < 4; ++ni) {
            int gc = col0 + ni * 16 + lr;
            float bv = bias[gc];
#pragma unroll
            for (int r = 0; r < 4; ++r) {
                int gr = row0 + wm + mi * 16 + lq * 4 + r;
                size_t idx = (size_t)gr * N + gc;
                if (kh == 0) C[idx] = acc[mi][ni][r] + bv + aux[idx];
                else         P[idx] = acc[mi][ni][r];
            }
        }
    }
}

// C += P, float4-wide. grid = MROWS*EE/4/256 = 4096 blocks.
__global__ __launch_bounds__(256) void add_inplace_kernel(
        float* __restrict__ C, const float* __restrict__ P) {
    int idx = blockIdx.x * 256 + threadIdx.x;
    float4 c = ((const float4*)C)[idx];
    float4 p = ((const float4*)P)[idx];
    c.x += p.x; c.y += p.y; c.z += p.z; c.w += p.w;
    ((float4*)C)[idx] = c;
}

// ---------------------------------------------------------------------------
// Fused FFN GEMM, 8-phase schedule (T2+T3+T4+T5), swizzled + B-reg-reuse.
// Unchanged from round 4/5 (89.7us, 0 bank conflicts, passing).
// ---------------------------------------------------------------------------
#define FFN_RD_A(KH, MH) \
    { const short* Ap = &Ab[buf][KH][0]; \
      af[0] = *(const short8*)&Ap[(wr * 128 + ((MH) * 4 + 0) * 16 + lr) * 32 + cs8]; \
      af[1] = *(const short8*)&Ap[(wr * 128 + ((MH) * 4 + 1) * 16 + lr) * 32 + cs8]; \
      af[2] = *(const short8*)&Ap[(wr * 128 + ((MH) * 4 + 2) * 16 + lr) * 32 + cs8]; \
      af[3] = *(const short8*)&Ap[(wr * 128 + ((MH) * 4 + 3) * 16 + lr) * 32 + cs8]; }

#define FFN_RD_B(KH) \
    { const short* Bp = &Bb[buf][KH][0]; \
      gf[0] = *(const short8*)&Bp[(wc * 32 + lr) * 32 + cs8]; \
      gf[1] = *(const short8*)&Bp[(wc * 32 + 16 + lr) * 32 + cs8]; \
      uf[0] = *(const short8*)&Bp[4096 + (wc * 32 + lr) * 32 + cs8]; \
      uf[1] = *(const short8*)&Bp[4096 + (wc * 32 + 16 + lr) * 32 + cs8]; }

#define FFN_MM(MH) \
    __builtin_amdgcn_s_setprio(1); \
    { _Pragma("unroll") for (int mi = 0; mi < 4; ++mi) { \
        ag[(MH) * 4 + mi][0] = __builtin_amdgcn_mfma_f32_16x16x32_bf16(af[mi], gf[0], ag[(MH) * 4 + mi][0], 0, 0, 0); \
        ag[(MH) * 4 + mi][1] = __builtin_amdgcn_mfma_f32_16x16x32_bf16(af[mi], gf[1], ag[(MH) * 4 + mi][1], 0, 0, 0); \
        au[(MH) * 4 + mi][0] = __builtin_amdgcn_mfma_f32_16x16x32_bf16(af[mi], uf[0], au[(MH) * 4 + mi][0], 0, 0, 0); \
        au[(MH) * 4 + mi][1] = __builtin_amdgcn_mfma_f32_16x16x32_bf16(af[mi], uf[1], au[(MH) * 4 + mi][1], 0, 0, 0); } } \
    __builtin_amdgcn_s_setprio(0);

__global__ __launch_bounds__(512, 2) void gemm_ffn_kernel(
        const bf16* __restrict__ A, const bf16* __restrict__ Bg,
        const bf16* __restrict__ Bu, const float* __restrict__ biasg,
        const float* __restrict__ biasu, bf16* __restrict__ C, int K) {
    __shared__ short Ab[2][2][8192];   // [buf][khalf][256 rows x 32 cols, swz]
    __shared__ short Bb[2][2][8192];   // [buf][khalf][G 128 | U 128, swz]

    const int tid = threadIdx.x;
    const int w = tid >> 6, lane = tid & 63;
    const int wr = w >> 2, wc = w & 3;           // 2M x 4N waves
    const int lr = lane & 15, quad = lane >> 4;
    const int row0 = blockIdx.y * 256, col0 = blockIdx.x * 128;
    const int NT = K >> 6;                       // 16 K-tiles
    const int cs8 = (quad ^ ((lr >> 1) & 3)) * 8;   // swizzled read chunk

    const int sr = tid >> 2;                     // staging row 0..127
    const int scs = (((tid & 3) ^ ((tid >> 3) & 3))) * 8;

    auto stageA = [&](short* dst, int kcol) {
        __builtin_amdgcn_global_load_lds(
            (gas_t)(A + (size_t)(row0 + sr) * K + kcol + scs),
            (las_t)(dst + tid * 8), 16, 0, 0);
        __builtin_amdgcn_global_load_lds(
            (gas_t)(A + (size_t)(row0 + 128 + sr) * K + kcol + scs),
            (las_t)(dst + 4096 + tid * 8), 16, 0, 0);
    };
    auto stageB = [&](short* dst, int kcol) {
        __builtin_amdgcn_global_load_lds(
            (gas_t)(Bg + (size_t)(col0 + sr) * K + kcol + scs),
            (las_t)(dst + tid * 8), 16, 0, 0);
        __builtin_amdgcn_global_load_lds(
            (gas_t)(Bu + (size_t)(col0 + sr) * K + kcol + scs),
            (las_t)(dst + 4096 + tid * 8), 16, 0, 0);
    };

    floatx4 ag[8][2], au[8][2];
#pragma unroll
    for (int mi = 0; mi < 8; ++mi)
#pragma unroll
        for (int ni = 0; ni < 2; ++ni) {
            ag[mi][ni] = (floatx4){0.f, 0.f, 0.f, 0.f};
            au[mi][ni] = (floatx4){0.f, 0.f, 0.f, 0.f};
        }

    // prologue: 6 half-tiles; drain to 8 outstanding (t0A0,t0B0 landed)
    stageA(&Ab[0][0][0], 0);
    stageB(&Bb[0][0][0], 0);
    stageA(&Ab[0][1][0], 32);
    stageB(&Bb[0][1][0], 32);
    stageA(&Ab[1][0][0], 64);
    stageB(&Bb[1][0][0], 64);
    VMC(8);
    BAR;

    for (int k = 0; k < NT; ++k) {
        const int buf = k & 1;
        short8 gf[2], uf[2];
        {   // phase 1: kh0, mh0 | read af + gf/uf(kh0) | stage tile k+1 A-k1
            short8 af[4];
            FFN_RD_A(0, 0)
            FFN_RD_B(0)
            if (k + 1 < NT) stageA(&Ab[buf ^ 1][1][0], (k + 1) * 64 + 32);
            BAR; WLG;
            FFN_MM(0)
            BAR;
        }
        {   // phase 2: kh0, mh1 | af only (gf/uf in regs) | stage k+1 B-k1
            short8 af[4];
            FFN_RD_A(0, 1)
            if (k + 1 < NT) stageB(&Bb[buf ^ 1][1][0], (k + 1) * 64 + 32);
            BAR; WLG;
            FFN_MM(1)
            if (k < NT - 1) { VMC(8); } else { VMC(0); }
            BAR;
        }
        {   // phase 3: kh1, mh0 | read af + gf/uf(kh1) | stage k+2 A-k0
            short8 af[4];
            FFN_RD_A(1, 0)
            FFN_RD_B(1)
            if (k + 2 < NT) stageA(&Ab[buf][0][0], (k + 2) * 64);
            BAR; WLG;
            FFN_MM(0)
            BAR;
        }
        {   // phase 4: kh1, mh1 | af only | stage k+2 B-k0
            short8 af[4];
            FFN_RD_A(1, 1)
            if (k + 2 < NT) stageB(&Bb[buf][0][0], (k + 2) * 64);
            BAR; WLG;
            FFN_MM(1)
            if (k < NT - 2) { VMC(8); } else if (k == NT - 2) { VMC(4); }
            BAR;
        }
    }

#pragma unroll
    for (int mi = 0; mi < 8; ++mi) {
#pragma unroll
        for (int ni = 0; ni < 2; ++ni) {
            int gc = col0 + wc * 32 + ni * 16 + lr;
            float bg_ = biasg[gc], bu_ = biasu[gc];
#pragma unroll
            for (int r = 0; r < 4; ++r) {
                int gr = row0 + wr * 128 + mi * 16 + quad * 4 + r;
                float g = ag[mi][ni][r] + bg_;
                float u = au[mi][ni][r] + bu_;
                float v = 0.5f * g * (1.0f + erff(g * 0.70710678118654752f)) * u;
                C[(size_t)gr * FFF + gc] = __float2bfloat16(v);
            }
        }
    }
}

// ---------------------------------------------------------------------------
// prep_v: vb bf16 (MROWS,64) -> vtb bf16 (BB,64,SS) transposed per batch.
// ---------------------------------------------------------------------------
__global__ __launch_bounds__(256) void prep_v_kernel(const bf16* __restrict__ vb,
                                                     bf16* __restrict__ vtb) {
    __shared__ short t[64][65];
    int s0 = blockIdx.x * 64, b = blockIdx.y;
    int tid = threadIdx.x;
    const short* vs = (const short*)vb;
    short* vd = (short*)vtb;
    for (int i = tid; i < 4096; i += 256) {
        int s = i >> 6, d = i & 63;
        t[d][s] = vs[((size_t)(b * SS + s0 + s)) * 64 + d];
    }
    __syncthreads();
    for (int i = tid; i < 4096; i += 256) {
        int d = i >> 6, sl = i & 63;
        vd[((size_t)(b * 64 + d)) * SS + s0 + sl] = t[d][sl];
    }
}

// ---------------------------------------------------------------------------
// MFMA flash attention v6: fixed-shift softmax + k-split-2 (unchanged math)
// with LDS-staged, double-buffered K/V tiles. XOR-swizzled (both-sides).
// ---------------------------------------------------------------------------
#define PST 68
#define SM_SHIFT 6.0f

__global__ __launch_bounds__(256, 3) void attn_mfma_kernel(
        const bf16* __restrict__ q, const bf16* __restrict__ kb,
        const bf16* __restrict__ vt,
        float* __restrict__ O0p, float* __restrict__ O1p,
        float* __restrict__ l0p, float* __restrict__ l1p) {
    __shared__ short Kb_s[2][64 * 64];
    __shared__ short Vb_s[2][64 * 64];
    __shared__ short Ps[4][16 * PST];

    int h = blockIdx.y, b = blockIdx.z;
    int px = blockIdx.x >> 1, half = blockIdx.x & 1;
    int tid = threadIdx.x, w = tid >> 6, lane = tid & 63;
    int lr = lane & 15, quad = lane >> 4;
    int rsw = lane & 7;                 // read-side swizzle: row&7 == lr&7

    float* __restrict__ Op = half ? O1p : O0p;
    float* __restrict__ lp = half ? l1p : l0p;

    const bf16* kbB = kb + (size_t)b * SS * 64;
    const bf16* vtB = vt + (size_t)b * 64 * SS;

    int st_sub = lane >> 3;
    int st_col = ((lane & 7) ^ st_sub) << 3;      // element offset within row

    auto stage_tile = [&](int nxt, int j0s) {
#pragma unroll
        for (int i = 0; i < 2; ++i) {
            int rr = i * 32 + w * 8 + st_sub;
            __builtin_amdgcn_global_load_lds(
                (gas_t)(kbB + (size_t)(j0s + rr) * 64 + st_col),
                (las_t)&Kb_s[nxt][(i * 256 + w * 64) * 8], 16, 0, 0);
            __builtin_amdgcn_global_load_lds(
                (gas_t)(vtB + (size_t)rr * SS + j0s + st_col),
                (las_t)&Vb_s[nxt][(i * 256 + w * 64) * 8], 16, 0, 0);
        }
    };

    for (int pass = 0; pass < 2; ++pass) {
        int qt = (pass == 0) ? px : (SS / 64 - 1 - px);
        int q0 = qt * 64;

        const bf16* qrow = q + ((size_t)(b * SS + q0 + w * 16 + lr)) * (HH * HD) + h * HD;
        short8 qf0 = *(const short8*)(qrow + quad * 8);
        short8 qf1 = *(const short8*)(qrow + 32 + quad * 8);

        int n  = qt + 1;            // total k-tiles for this q-tile
        int n0 = (n + 1) >> 1;      // half 0 takes [0,n0), half 1 takes [n0,n)
        int tlo = half ? n0 : 0;
        int thi = half ? n  : n0;

        floatx4 O[4];
#pragma unroll
        for (int ni = 0; ni < 4; ++ni) O[ni] = (floatx4){0.f, 0.f, 0.f, 0.f};
        float lrow[4] = {0.f, 0.f, 0.f, 0.f};

        int cur = 0;
        if (tlo < thi) stage_tile(0, tlo * 64);
        __syncthreads();

        for (int t = tlo; t < thi; ++t) {
            // stage next tile into the other buffer (overlaps this compute)
            if (t + 1 < thi) stage_tile(cur ^ 1, (t + 1) * 64);

            int j0 = t * 64;

            // S = Q @ K^T   (K fragments from swizzled LDS)
            floatx4 S[4];
#pragma unroll
            for (int ni = 0; ni < 4; ++ni) S[ni] = (floatx4){0.f, 0.f, 0.f, 0.f};
#pragma unroll
            for (int ni = 0; ni < 4; ++ni) {
                const short* Kc = &Kb_s[cur][(ni * 16 + lr) * 64];
                short8 b0 = *(const short8*)&Kc[(quad ^ rsw) * 8];
                short8 b1 = *(const short8*)&Kc[((quad ^ rsw) ^ 4) * 8];
                S[ni] = __builtin_amdgcn_mfma_f32_16x16x32_bf16(qf0, b0, S[ni], 0, 0, 0);
                S[ni] = __builtin_amdgcn_mfma_f32_16x16x32_bf16(qf1, b1, S[ni], 0, 0, 0);
            }

            // V fragments (swizzled LDS), issued early to overlap exp + pack
            short8 vf[8];
#pragma unroll
            for (int ni = 0; ni < 4; ++ni) {
                const short* Vc = &Vb_s[cur][(ni * 16 + lr) * 64];
                vf[2 * ni]     = *(const short8*)&Vc[(quad ^ rsw) * 8];
                vf[2 * ni + 1] = *(const short8*)&Vc[((quad ^ rsw) ^ 4) * 8];
            }

            // causal mask on diagonal tile
            if (t == qt) {
                int rowg = q0 + w * 16 + quad * 4;
#pragma unroll
                for (int ni = 0; ni < 4; ++ni) {
                    int colg = j0 + ni * 16 + lr;
#pragma unroll
                    for (int r = 0; r < 4; ++r)
                        if (colg > rowg + r) S[ni][r] = -3.0e38f;
                }
            }

            // fixed-shift exp; accumulate per-lane row sums (no cross-lane ops)
#pragma unroll
            for (int ni = 0; ni < 4; ++ni)
#pragma unroll
                for (int r = 0; r < 4; ++r)
                    S[ni][r] = __expf(S[ni][r] - SM_SHIFT);
#pragma unroll
            for (int r = 0; r < 4; ++r)
                lrow[r] += S[0][r] + S[1][r] + S[2][r] + S[3][r];

            // pack P (bf16) to wave-private LDS in C-layout
#pragma unroll
            for (int ni = 0; ni < 4; ++ni)
#pragma unroll
                for (int r = 0; r < 4; ++r) {
                    bf16 pb = __float2bfloat16(S[ni][r]);
                    Ps[w][(quad * 4 + r) * PST + ni * 16 + lr] = *(short*)&pb;
                }
            short4v a0 = *(const short4v*)&Ps[w][lr * PST + quad * 8];
            short4v a1 = *(const short4v*)&Ps[w][lr * PST + quad * 8 + 4];
            short4v a2 = *(const short4v*)&Ps[w][lr * PST + 32 + quad * 8];
            short4v a3 = *(const short4v*)&Ps[w][lr * PST + 32 + quad * 8 + 4];
            short8 p0 = __builtin_shufflevector(a0, a1, 0, 1, 2, 3, 4, 5, 6, 7);
            short8 p1 = __builtin_shufflevector(a2, a3, 0, 1, 2, 3, 4, 5, 6, 7);

            // O += P @ V
#pragma unroll
            for (int ni = 0; ni < 4; ++ni) {
                O[ni] = __builtin_amdgcn_mfma_f32_16x16x32_bf16(p0, vf[2 * ni], O[ni], 0, 0, 0);
                O[ni] = __builtin_amdgcn_mfma_f32_16x16x32_bf16(p1, vf[2 * ni + 1], O[ni], 0, 0, 0);
            }

            // drains next-tile staging + ensures all waves done with cur
            __syncthreads();
            cur ^= 1;
        }

        // deferred row-sum reduction over the quad's 16 lanes (once per pass)
#pragma unroll
        for (int r = 0; r < 4; ++r) {
            float l = lrow[r];
            for (int off = 1; off < 16; off <<= 1) l += __shfl_xor(l, off, 64);
            lrow[r] = l;
        }

        // write unnormalized partials (zeros when this half's range is empty)
#pragma unroll
        for (int ni = 0; ni < 4; ++ni) {
            int gc = h * 64 + ni * 16 + lr;
#pragma unroll
            for (int r = 0; r < 4; ++r) {
                int gr = b * SS + q0 + w * 16 + quad * 4 + r;
                Op[(size_t)gr * (HH * HD) + gc] = O[ni][r];
            }
        }
        if (lr == 0) {
#pragma unroll
            for (int r = 0; r < 4; ++r) {
                int gr = b * SS + q0 + w * 16 + quad * 4 + r;
                lp[(size_t)gr * HH + h] = lrow[r];
            }
        }
    }
}

// ---------------------------------------------------------------------------
// Combine the two key-range halves: ao = (O0+O1)/(l0+l1), bf16 out.
// ---------------------------------------------------------------------------
__global__ __launch_bounds__(256) void attn_combine_kernel(
        const float* __restrict__ O0p, const float* __restrict__ O1p,
        const float* __restrict__ l0p, const float* __restrict__ l1p,
        bf16* __restrict__ o) {
    int idx = blockIdx.x * 256 + threadIdx.x;   // < MROWS*1024/4
    int d4  = idx & 15;
    int hh  = (idx >> 4) & 15;
    int row = idx >> 8;
    float l = l0p[row * HH + hh] + l1p[row * HH + hh];
    float inv = 1.0f / l;
    size_t base = (size_t)row * (HH * HD) + hh * 64 + d4 * 4;
    float4 a = *(const float4*)(O0p + base);
    float4 c = *(const float4*)(O1p + base);
    short4v o4;
    {
        bf16 v0 = __float2bfloat16((a.x + c.x) * inv);
        bf16 v1 = __float2bfloat16((a.y + c.y) * inv);
        bf16 v2 = __float2bfloat16((a.z + c.z) * inv);
        bf16 v3 = __float2bfloat16((a.w + c.w) * inv);
        o4[0] = *(short*)&v0; o4[1] = *(short*)&v1;
        o4[2] = *(short*)&v2; o4[3] = *(short*)&v3;
    }
    *(short4v*)(o + base) = o4;
}

// ---------------------------------------------------------------------------
// Launch (14 dispatches). Workspace lifetimes (byte offsets, high-water 87MB):
//   pbuf @0 (16MB fp32): wo partial (after qbf dies) / wd partial (after wgT
//     dies). qbf @0 (8MB) lives qkv_combine->attn. wgT @0 lives ffn_w->ffn.
//   p1q @8M (19MB): qkv partial half-1 (dead before wuT@8M / x2@16M written).
//   x2 @16M (fp32 16MB): wo output, live to wd. Opart0 @16M during attn.
//   h1b/h2b @32M | vb @40M | ao @42M (wdT reuses after wo)
//   gg @50M (32MB, FFN out). Pre-FFN its body hosts: kbf@50M, vtb@50.5M,
//     p0q@51M (19MB, qkv half-0; dead after combine), Opart1@51M (attn),
//     lparts@67M, ctab/stab@70M — all dead before gg written.
//   wqkvT @82M | bqkv @84.5M | woT @85M
// ---------------------------------------------------------------------------
#define MB (1024ull * 1024ull)

extern "C" void kernel_launch(void* const* d_in, const int* in_sizes, int n_in,
                              void* d_out, int out_size, void* d_ws, size_t ws_size,
                              hipStream_t stream) {
    const float* x  = (const float*)d_in[0];
    const float* wq = (const float*)d_in[1];
    const float* bq = (const float*)d_in[2];
    const float* wk = (const float*)d_in[3];
    const float* bk = (const float*)d_in[4];
    const float* wv = (const float*)d_in[5];
    const float* bv = (const float*)d_in[6];
    const float* wo = (const float*)d_in[7];
    const float* bo = (const float*)d_in[8];
    const float* wg = (const float*)d_in[9];
    const float* bg = (const float*)d_in[10];
    const float* wu = (const float*)d_in[11];
    const float* bu = (const float*)d_in[12];
    const float* wd = (const float*)d_in[13];
    const float* bd = (const float*)d_in[14];
    const float* g1 = (const float*)d_in[15];
    const float* g2 = (const float*)d_in[16];
    float* out = (float*)d_out;

    char* ws = (char*)d_ws;
    float* pbuf  = (float*)(ws);                       // 16MB split-K partial
    bf16*  qbf   = (bf16*)(ws);                        // 8MB (combine->attn)
    float* p1q   = (float*)(ws + 8 * MB);              // 19MB qkv half-1
    bf16*  wuT   = (bf16*)(ws + 8 * MB);
    float* x2    = (float*)(ws + 16 * MB);
    bf16*  h1b   = (bf16*)(ws + 32 * MB);
    bf16*  vb    = (bf16*)(ws + 40 * MB);
    bf16*  ao    = (bf16*)(ws + 42 * MB);
    bf16*  gg    = (bf16*)(ws + 50 * MB);
    bf16*  kbf   = (bf16*)(ws + 50 * MB);
    bf16*  vtb   = (bf16*)(ws + 50 * MB + 512 * 1024);
    float* p0q   = (float*)(ws + 51 * MB);             // 19MB qkv half-0
    float* Opart0 = (float*)(ws + 16 * MB);            // over x2 (attn phase)
    float* Opart1 = (float*)(ws + 51 * MB);            // over p0q (attn phase)
    float* lpart0 = (float*)(ws + 67 * MB);
    float* lpart1 = (float*)(ws + 67 * MB + 256 * 1024);
    float* ctab   = (float*)(ws + 70 * MB);
    float* stab   = (float*)(ws + 70 * MB + 256 * 1024);
    bf16*  wqkvT = (bf16*)(ws + 82 * MB);
    float* bqkv  = (float*)(ws + 84 * MB + 512 * 1024);
    bf16*  woT   = (bf16*)(ws + 85 * MB);
    bf16*  wgT   = (bf16*)(ws);                        // over qbf/pbuf (post-attn)
    bf16*  wdT   = (bf16*)(ws + 42 * MB);              // over ao (post-wo)
    bf16*  h2b   = h1b;

    // 1. fused attention-side weight prep
    prep_weights_kernel<<<2437, 256, 0, stream>>>(
        wq, wk, wv, wo, bq, bk, bv, wqkvT, woT, bqkv, ctab, stab);

    // 2. h1 = rmsnorm(x, g1)
    rmsnorm_kernel<<<MROWS, 256, 0, stream>>>(x, g1, h1b, EE);

    // 3. QKV projection, split-K=2 -> fp32 partials
    gemm_qkv_kernel<<<dim3(NQKV / 128, MROWS / 128, 2), 256, 0, stream>>>(
        h1b, wqkvT, p0q, p1q, EE);

    // 4. combine + bias + RoPE -> qbf, kbf, vb
    qkv_combine_kernel<<<dim3(3, MROWS), 192, 0, stream>>>(
        p0q, p1q, bqkv, ctab, stab, qbf, kbf, vb);

    // 5. v transpose -> vtb
    prep_v_kernel<<<dim3(SS / 64, BB), 256, 0, stream>>>(vb, vtb);

    // 6. attention partials (k-split x2) + combine -> ao [bf16]
    attn_mfma_kernel<<<dim3(2 * SS / 128, HH, BB), 256, 0, stream>>>(
        qbf, kbf, vtb, Opart0, Opart1, lpart0, lpart1);
    attn_combine_kernel<<<(MROWS * HH * HD / 4) / 256, 256, 0, stream>>>(
        Opart0, Opart1, lpart0, lpart1, ao);

    // 7. x2 = ao @ wo + bo + x  [split-K=2 + join]
    gemm_n64_split_kernel<<<dim3(EE / 64, MROWS / 128, 2), 256, 0, stream>>>(
        ao, woT, bo, x, x2, pbuf, EE, EE);
    add_inplace_kernel<<<(MROWS * EE / 4) / 256, 256, 0, stream>>>(x2, pbuf);

    // 8. h2 = rmsnorm(x2, g2)
    rmsnorm_kernel<<<MROWS, 256, 0, stream>>>(x2, g2, h2b, EE);

    // 9. fused FFN weight prep (qbf/pbuf + p1q + ao now dead)
    ffn_weights_kernel<<<12288, 256, 0, stream>>>(wg, wu, wd, wgT, wuT, wdT);

    // 10. gg = gelu(h2@wg+bg) * (h2@wu+bu)  [8-phase + swizzle]
    gemm_ffn_kernel<<<dim3(FFF / 128, MROWS / 256), 512, 0, stream>>>(
        h2b, wgT, wuT, bg, bu, gg, EE);

    // 11. out = gg @ wd + bd + x2  [split-K=2 + join; wgT dead -> pbuf]
    gemm_n64_split_kernel<<<dim3(EE / 64, MROWS / 128, 2), 256, 0, stream>>>(
        gg, wdT, bd, x2, out, pbuf, EE, FFF);
    add_inplace_kernel<<<(MROWS * EE / 4) / 256, 256, 0, stream>>>(out, pbuf);
}

// Round 7
// 411.837 us; speedup vs baseline: 1.0185x; 1.0185x over previous
//
#include <hip/hip_runtime.h>
#include <hip/hip_bf16.h>
#include <math.h>

// Problem constants
#define BB 2
#define SS 2048
#define EE 1024
#define HH 16
#define HD 64
#define FFF 4096
#define MROWS (BB * SS)        // 4096
#define EPS_F 1.1920929e-7f
#define NQKV 1152              // 1024 q + 64 k + 64 v

typedef __hip_bfloat16 bf16;
typedef __attribute__((ext_vector_type(8))) short short8;
typedef __attribute__((ext_vector_type(4))) short short4v;
typedef __attribute__((ext_vector_type(4))) float floatx4;

typedef const __attribute__((address_space(1))) void* gas_t;
typedef __attribute__((address_space(3))) void* las_t;

// scheduling primitives for the 8-phase FFN kernel
#define BAR __builtin_amdgcn_s_barrier()
#define WLG do { asm volatile("s_waitcnt lgkmcnt(0)" ::: "memory"); \
                 __builtin_amdgcn_sched_barrier(0); } while (0)
#define VMC(N) asm volatile("s_waitcnt vmcnt(" #N ")" ::: "memory")

// ---------------------------------------------------------------------------
// RMSNorm: fp32 in, bf16 out. float4-vectorized (cols == 1024 == 256*4).
// ---------------------------------------------------------------------------
__global__ __launch_bounds__(256) void rmsnorm_kernel(const float* __restrict__ x,
                                                      const float* __restrict__ g,
                                                      bf16* __restrict__ out,
                                                      int cols) {
    int row = blockIdx.x, tid = threadIdx.x;
    const float4* xr = (const float4*)(x + (size_t)row * cols);
    float4 v = xr[tid];
    float ss = v.x * v.x + v.y * v.y + v.z * v.z + v.w * v.w;
    for (int off = 32; off > 0; off >>= 1) ss += __shfl_xor(ss, off, 64);
    __shared__ float red[4];
    int wave = tid >> 6;
    if ((tid & 63) == 0) red[wave] = ss;
    __syncthreads();
    float tot = red[0] + red[1] + red[2] + red[3];
    float rs = rsqrtf(tot / (float)cols + EPS_F);
    float4 gv = ((const float4*)g)[tid];
    short4v o;
    {
        bf16 b0 = __float2bfloat16(v.x * rs * gv.x);
        bf16 b1 = __float2bfloat16(v.y * rs * gv.y);
        bf16 b2 = __float2bfloat16(v.z * rs * gv.z);
        bf16 b3 = __float2bfloat16(v.w * rs * gv.w);
        o[0] = *(short*)&b0; o[1] = *(short*)&b1;
        o[2] = *(short*)&b2; o[3] = *(short*)&b3;
    }
    *(short4v*)(out + (size_t)row * cols + tid * 4) = o;
}

// ---------------------------------------------------------------------------
// 32x32 transpose+cast tile body (shared by the two fused weight-prep kernels)
// ---------------------------------------------------------------------------
__device__ __forceinline__ void transpose_tile32(const float* __restrict__ W,
                                                 bf16* __restrict__ Wt,
                                                 int K, int N, int bx, int by,
                                                 int tid, float (*t)[33]) {
    int n0 = bx * 32, k0 = by * 32;
    int tx = tid & 31, ty = tid >> 5;   // ty 0..7
#pragma unroll
    for (int i = 0; i < 4; ++i) {
        int kk = ty + i * 8;
        t[kk][tx] = W[(size_t)(k0 + kk) * N + n0 + tx];
    }
    __syncthreads();
#pragma unroll
    for (int i = 0; i < 4; ++i) {
        int nn = ty + i * 8;
        Wt[(size_t)(n0 + nn) * K + k0 + tx] = __float2bfloat16(t[tx][nn]);
    }
}

// ---------------------------------------------------------------------------
// Fused attention-side prep (1 launch):
//   wq/wk/wv/wo transposes + [bq|bk|bv] pack + RoPE cos/sin tables.
// Block ranges: [0,1024) wq | [1024,1088) wk | [1088,1152) wv |
//               [1152,2176) wo | [2176,2432) rope table | [2432,2437) pack.
// ---------------------------------------------------------------------------
__global__ __launch_bounds__(256) void prep_weights_kernel(
        const float* __restrict__ wq, const float* __restrict__ wk,
        const float* __restrict__ wv, const float* __restrict__ wo,
        const float* __restrict__ bq, const float* __restrict__ bk,
        const float* __restrict__ bv,
        bf16* __restrict__ wqkvT, bf16* __restrict__ woT,
        float* __restrict__ bqkv, float* __restrict__ ct, float* __restrict__ st) {
    __shared__ float t[32][33];
    int bid = blockIdx.x, tid = threadIdx.x;
    if (bid < 1024) {
        transpose_tile32(wq, wqkvT, EE, EE, bid & 31, bid >> 5, tid, t);
    } else if (bid < 1088) {
        int b2 = bid - 1024;
        transpose_tile32(wk, wqkvT + (size_t)1024 * EE, EE, HD, b2 & 1, b2 >> 1, tid, t);
    } else if (bid < 1152) {
        int b2 = bid - 1088;
        transpose_tile32(wv, wqkvT + (size_t)1088 * EE, EE, HD, b2 & 1, b2 >> 1, tid, t);
    } else if (bid < 2176) {
        int b2 = bid - 1152;
        transpose_tile32(wo, woT, EE, EE, b2 & 31, b2 >> 5, tid, t);
    } else if (bid < 2432) {
        int idx = (bid - 2176) * 256 + tid;       // SS*32 = 65536 entries
        int i = idx & 31, s = idx >> 5;
        float inv = powf(10000.0f, -(float)i / 32.0f);
        float ang = (float)s * inv;
        ct[idx] = cosf(ang);
        st[idx] = sinf(ang);
    } else {
        int tt = (bid - 2432) * 256 + tid;
        if (tt < NQKV) {
            float v;
            if (tt < 1024)      v = bq[tt];
            else if (tt < 1088) v = bk[tt - 1024];
            else                v = bv[tt - 1088];
            bqkv[tt] = v;
        }
    }
}

// ---------------------------------------------------------------------------
// Fused FFN weight prep (1 launch): wg/wu/wd transposes.
// [0,4096) wg | [4096,8192) wu | [8192,12288) wd.
// ---------------------------------------------------------------------------
__global__ __launch_bounds__(256) void ffn_weights_kernel(
        const float* __restrict__ wg, const float* __restrict__ wu,
        const float* __restrict__ wd,
        bf16* __restrict__ wgT, bf16* __restrict__ wuT, bf16* __restrict__ wdT) {
    __shared__ float t[32][33];
    int bid = blockIdx.x, tid = threadIdx.x;
    if (bid < 4096) {
        transpose_tile32(wg, wgT, EE, FFF, bid & 127, bid >> 7, tid, t);
    } else if (bid < 8192) {
        int b2 = bid - 4096;
        transpose_tile32(wu, wuT, EE, FFF, b2 & 127, b2 >> 7, tid, t);
    } else {
        int b2 = bid - 8192;
        transpose_tile32(wd, wdT, FFF, EE, b2 & 31, b2 >> 5, tid, t);
    }
}

// ---------------------------------------------------------------------------
// Fused QKV GEMM + RoPE epilogue (round-5 form, proven 415us config):
// [q|k|v] = h1 @ [wq|wk|wv]^T + bqkv; q-rope (x0.125) / k-rope in registers
// (acc[mi][ni] and acc[mi][ni+2] are the (i,i+32) rotation pair).
// ---------------------------------------------------------------------------
#define GK 64

__global__ __launch_bounds__(256) void gemm_qkv_kernel(
        const bf16* __restrict__ A, const bf16* __restrict__ Bt,
        const float* __restrict__ bias,
        const float* __restrict__ ct, const float* __restrict__ st,
        bf16* __restrict__ qout, bf16* __restrict__ kout,
        bf16* __restrict__ vout, int K) {
    __shared__ short As[128 * GK];
    __shared__ short Bs[128 * GK];
    int tid = threadIdx.x;
    int wave = tid >> 6, lane = tid & 63;
    int wm = (wave >> 1) * 64, wn = (wave & 1) * 64;
    int row0 = blockIdx.y * 128, col0 = blockIdx.x * 128;
    int lr = lane & 15, lq = lane >> 4;

    int srow = wave * 32 + (lane >> 3);
    int scol = (lane & 7) * 8;
    const bf16* Abase = A + (size_t)(row0 + srow) * K + scol;
    const bf16* Bbase = Bt + (size_t)(col0 + srow) * K + scol;

    floatx4 acc[4][4];
#pragma unroll
    for (int mi = 0; mi < 4; ++mi)
#pragma unroll
        for (int ni = 0; ni < 4; ++ni)
            acc[mi][ni] = (floatx4){0.f, 0.f, 0.f, 0.f};

    for (int k0 = 0; k0 < K; k0 += GK) {
        __syncthreads();
#pragma unroll
        for (int c = 0; c < 4; ++c) {
            __builtin_amdgcn_global_load_lds(
                (gas_t)(Abase + (size_t)(c * 8) * K + k0),
                (las_t)&As[(wave * 32 + c * 8) * GK], 16, 0, 0);
            __builtin_amdgcn_global_load_lds(
                (gas_t)(Bbase + (size_t)(c * 8) * K + k0),
                (las_t)&Bs[(wave * 32 + c * 8) * GK], 16, 0, 0);
        }
        __syncthreads();
#pragma unroll
        for (int ks = 0; ks < GK; ks += 32) {
            short8 af[4], bfr[4];
#pragma unroll
            for (int mi = 0; mi < 4; ++mi)
                af[mi] = *(const short8*)&As[(wm + mi * 16 + lr) * GK + ks + lq * 8];
#pragma unroll
            for (int ni = 0; ni < 4; ++ni)
                bfr[ni] = *(const short8*)&Bs[(wn + ni * 16 + lr) * GK + ks + lq * 8];
#pragma unroll
            for (int mi = 0; mi < 4; ++mi)
#pragma unroll
                for (int ni = 0; ni < 4; ++ni)
                    acc[mi][ni] = __builtin_amdgcn_mfma_f32_16x16x32_bf16(
                        af[mi], bfr[ni], acc[mi][ni], 0, 0, 0);
        }
    }

    int hcol = col0 + wn;                 // 64-aligned head-span base
    if (hcol < 1088) {                    // q (hcol<1024) or k (hcol==1024)
        bool isQ = hcol < 1024;
#pragma unroll
        for (int mi = 0; mi < 4; ++mi) {
#pragma unroll
            for (int ni = 0; ni < 2; ++ni) {
                int i = ni * 16 + lr;
                float b1 = bias[hcol + i];
                float b2 = bias[hcol + i + 32];
#pragma unroll
                for (int r = 0; r < 4; ++r) {
                    int gr = row0 + wm + mi * 16 + lq * 4 + r;
                    int s = gr & (SS - 1);
                    float c  = ct[s * 32 + i];
                    float sn = st[s * 32 + i];
                    float t1 = acc[mi][ni][r] + b1;
                    float t2 = acc[mi][ni + 2][r] + b2;
                    float o1 = t1 * c - t2 * sn;
                    float o2 = t1 * sn + t2 * c;
                    if (isQ) {
                        qout[(size_t)gr * 1024 + hcol + i]      = __float2bfloat16(o1 * 0.125f);
                        qout[(size_t)gr * 1024 + hcol + i + 32] = __float2bfloat16(o2 * 0.125f);
                    } else {
                        kout[(size_t)gr * 64 + i]      = __float2bfloat16(o1);
                        kout[(size_t)gr * 64 + i + 32] = __float2bfloat16(o2);
                    }
                }
            }
        }
    } else {                              // v: plain bias + cast
#pragma unroll
        for (int mi = 0; mi < 4; ++mi)
#pragma unroll
            for (int ni = 0; ni < 4; ++ni) {
                int vcol = ni * 16 + lr;
                float bv_ = bias[1088 + vcol];
#pragma unroll
                for (int r = 0; r < 4; ++r) {
                    int gr = row0 + wm + mi * 16 + lq * 4 + r;
                    vout[(size_t)gr * 64 + vcol] = __float2bfloat16(acc[mi][ni][r] + bv_);
                }
            }
    }
}

// ---------------------------------------------------------------------------
// GEMM 128x64 tiles (for N=1024 outputs: wo, wd): C = A@Bt^T + bias + aux.
// Round-5 form (split-K experiment was neutral -> reverted, saves join traffic).
// ---------------------------------------------------------------------------
__global__ __launch_bounds__(256) void gemm_n64_kernel(
        const bf16* __restrict__ A, const bf16* __restrict__ Bt,
        const float* __restrict__ bias, const float* __restrict__ aux,
        float* __restrict__ C, int M, int N, int K) {
    __shared__ short As[128 * GK];
    __shared__ short Bs[64 * GK];
    int tid = threadIdx.x;
    int wave = tid >> 6, lane = tid & 63;
    int wm = wave * 32;
    int row0 = blockIdx.y * 128, col0 = blockIdx.x * 64;
    int lr = lane & 15, lq = lane >> 4;

    int srow = (lane >> 3);
    int scol = (lane & 7) * 8;
    const bf16* Abase = A + (size_t)(row0 + wave * 32 + srow) * K + scol;
    const bf16* Bbase = Bt + (size_t)(col0 + wave * 16 + srow) * K + scol;

    floatx4 acc[2][4];
#pragma unroll
    for (int mi = 0; mi < 2; ++mi)
#pragma unroll
        for (int ni = 0; ni < 4; ++ni)
            acc[mi][ni] = (floatx4){0.f, 0.f, 0.f, 0.f};

    for (int k0 = 0; k0 < K; k0 += GK) {
        __syncthreads();
#pragma unroll
        for (int c = 0; c < 4; ++c)
            __builtin_amdgcn_global_load_lds(
                (gas_t)(Abase + (size_t)(c * 8) * K + k0),
                (las_t)&As[(wave * 32 + c * 8) * GK], 16, 0, 0);
#pragma unroll
        for (int c = 0; c < 2; ++c)
            __builtin_amdgcn_global_load_lds(
                (gas_t)(Bbase + (size_t)(c * 8) * K + k0),
                (las_t)&Bs[(wave * 16 + c * 8) * GK], 16, 0, 0);
        __syncthreads();
#pragma unroll
        for (int ks = 0; ks < GK; ks += 32) {
            short8 af[2], bfr[4];
#pragma unroll
            for (int mi = 0; mi < 2; ++mi)
                af[mi] = *(const short8*)&As[(wm + mi * 16 + lr) * GK + ks + lq * 8];
#pragma unroll
            for (int ni = 0; ni < 4; ++ni)
                bfr[ni] = *(const short8*)&Bs[(ni * 16 + lr) * GK + ks + lq * 8];
#pragma unroll
            for (int mi = 0; mi < 2; ++mi)
#pragma unroll
                for (int ni = 0; ni < 4; ++ni)
                    acc[mi][ni] = __builtin_amdgcn_mfma_f32_16x16x32_bf16(
                        af[mi], bfr[ni], acc[mi][ni], 0, 0, 0);
        }
    }

#pragma unroll
    for (int mi = 0; mi < 2; ++mi) {
#pragma unroll
        for (int ni = 0; ni < 4; ++ni) {
            int gc = col0 + ni * 16 + lr;
            float bv = bias[gc];
#pragma unroll
            for (int r = 0; r < 4; ++r) {
                int gr = row0 + wm + mi * 16 + lq * 4 + r;
                size_t idx = (size_t)gr * N + gc;
                C[idx] = acc[mi][ni][r] + bv + aux[idx];
            }
        }
    }
}

// ---------------------------------------------------------------------------
// Fused FFN GEMM, 8-phase schedule (T2+T3+T4+T5), swizzled + B-reg-reuse.
// NOW TAKES rowoff: launched as TWO row-half dispatches (~45us each) so the
// bench top-5 can reveal the true #2 kernel (FFN x5 was masking everything).
// Identical per-element math and schedule; only the grid is split.
// ---------------------------------------------------------------------------
#define FFN_RD_A(KH, MH) \
    { const short* Ap = &Ab[buf][KH][0]; \
      af[0] = *(const short8*)&Ap[(wr * 128 + ((MH) * 4 + 0) * 16 + lr) * 32 + cs8]; \
      af[1] = *(const short8*)&Ap[(wr * 128 + ((MH) * 4 + 1) * 16 + lr) * 32 + cs8]; \
      af[2] = *(const short8*)&Ap[(wr * 128 + ((MH) * 4 + 2) * 16 + lr) * 32 + cs8]; \
      af[3] = *(const short8*)&Ap[(wr * 128 + ((MH) * 4 + 3) * 16 + lr) * 32 + cs8]; }

#define FFN_RD_B(KH) \
    { const short* Bp = &Bb[buf][KH][0]; \
      gf[0] = *(const short8*)&Bp[(wc * 32 + lr) * 32 + cs8]; \
      gf[1] = *(const short8*)&Bp[(wc * 32 + 16 + lr) * 32 + cs8]; \
      uf[0] = *(const short8*)&Bp[4096 + (wc * 32 + lr) * 32 + cs8]; \
      uf[1] = *(const short8*)&Bp[4096 + (wc * 32 + 16 + lr) * 32 + cs8]; }

#define FFN_MM(MH) \
    __builtin_amdgcn_s_setprio(1); \
    { _Pragma("unroll") for (int mi = 0; mi < 4; ++mi) { \
        ag[(MH) * 4 + mi][0] = __builtin_amdgcn_mfma_f32_16x16x32_bf16(af[mi], gf[0], ag[(MH) * 4 + mi][0], 0, 0, 0); \
        ag[(MH) * 4 + mi][1] = __builtin_amdgcn_mfma_f32_16x16x32_bf16(af[mi], gf[1], ag[(MH) * 4 + mi][1], 0, 0, 0); \
        au[(MH) * 4 + mi][0] = __builtin_amdgcn_mfma_f32_16x16x32_bf16(af[mi], uf[0], au[(MH) * 4 + mi][0], 0, 0, 0); \
        au[(MH) * 4 + mi][1] = __builtin_amdgcn_mfma_f32_16x16x32_bf16(af[mi], uf[1], au[(MH) * 4 + mi][1], 0, 0, 0); } } \
    __builtin_amdgcn_s_setprio(0);

__global__ __launch_bounds__(512, 2) void gemm_ffn_kernel(
        const bf16* __restrict__ A, const bf16* __restrict__ Bg,
        const bf16* __restrict__ Bu, const float* __restrict__ biasg,
        const float* __restrict__ biasu, bf16* __restrict__ C, int K, int rowoff) {
    __shared__ short Ab[2][2][8192];   // [buf][khalf][256 rows x 32 cols, swz]
    __shared__ short Bb[2][2][8192];   // [buf][khalf][G 128 | U 128, swz]

    const int tid = threadIdx.x;
    const int w = tid >> 6, lane = tid & 63;
    const int wr = w >> 2, wc = w & 3;           // 2M x 4N waves
    const int lr = lane & 15, quad = lane >> 4;
    const int row0 = (blockIdx.y + rowoff) * 256, col0 = blockIdx.x * 128;
    const int NT = K >> 6;                       // 16 K-tiles
    const int cs8 = (quad ^ ((lr >> 1) & 3)) * 8;   // swizzled read chunk

    const int sr = tid >> 2;                     // staging row 0..127
    const int scs = (((tid & 3) ^ ((tid >> 3) & 3))) * 8;

    auto stageA = [&](short* dst, int kcol) {
        __builtin_amdgcn_global_load_lds(
            (gas_t)(A + (size_t)(row0 + sr) * K + kcol + scs),
            (las_t)(dst + tid * 8), 16, 0, 0);
        __builtin_amdgcn_global_load_lds(
            (gas_t)(A + (size_t)(row0 + 128 + sr) * K + kcol + scs),
            (las_t)(dst + 4096 + tid * 8), 16, 0, 0);
    };
    auto stageB = [&](short* dst, int kcol) {
        __builtin_amdgcn_global_load_lds(
            (gas_t)(Bg + (size_t)(col0 + sr) * K + kcol + scs),
            (las_t)(dst + tid * 8), 16, 0, 0);
        __builtin_amdgcn_global_load_lds(
            (gas_t)(Bu + (size_t)(col0 + sr) * K + kcol + scs),
            (las_t)(dst + 4096 + tid * 8), 16, 0, 0);
    };

    floatx4 ag[8][2], au[8][2];
#pragma unroll
    for (int mi = 0; mi < 8; ++mi)
#pragma unroll
        for (int ni = 0; ni < 2; ++ni) {
            ag[mi][ni] = (floatx4){0.f, 0.f, 0.f, 0.f};
            au[mi][ni] = (floatx4){0.f, 0.f, 0.f, 0.f};
        }

    // prologue: 6 half-tiles; drain to 8 outstanding (t0A0,t0B0 landed)
    stageA(&Ab[0][0][0], 0);
    stageB(&Bb[0][0][0], 0);
    stageA(&Ab[0][1][0], 32);
    stageB(&Bb[0][1][0], 32);
    stageA(&Ab[1][0][0], 64);
    stageB(&Bb[1][0][0], 64);
    VMC(8);
    BAR;

    for (int k = 0; k < NT; ++k) {
        const int buf = k & 1;
        short8 gf[2], uf[2];
        {   // phase 1: kh0, mh0 | read af + gf/uf(kh0) | stage tile k+1 A-k1
            short8 af[4];
            FFN_RD_A(0, 0)
            FFN_RD_B(0)
            if (k + 1 < NT) stageA(&Ab[buf ^ 1][1][0], (k + 1) * 64 + 32);
            BAR; WLG;
            FFN_MM(0)
            BAR;
        }
        {   // phase 2: kh0, mh1 | af only (gf/uf in regs) | stage k+1 B-k1
            short8 af[4];
            FFN_RD_A(0, 1)
            if (k + 1 < NT) stageB(&Bb[buf ^ 1][1][0], (k + 1) * 64 + 32);
            BAR; WLG;
            FFN_MM(1)
            if (k < NT - 1) { VMC(8); } else { VMC(0); }
            BAR;
        }
        {   // phase 3: kh1, mh0 | read af + gf/uf(kh1) | stage k+2 A-k0
            short8 af[4];
            FFN_RD_A(1, 0)
            FFN_RD_B(1)
            if (k + 2 < NT) stageA(&Ab[buf][0][0], (k + 2) * 64);
            BAR; WLG;
            FFN_MM(0)
            BAR;
        }
        {   // phase 4: kh1, mh1 | af only | stage k+2 B-k0
            short8 af[4];
            FFN_RD_A(1, 1)
            if (k + 2 < NT) stageB(&Bb[buf][0][0], (k + 2) * 64);
            BAR; WLG;
            FFN_MM(1)
            if (k < NT - 2) { VMC(8); } else if (k == NT - 2) { VMC(4); }
            BAR;
        }
    }

#pragma unroll
    for (int mi = 0; mi < 8; ++mi) {
#pragma unroll
        for (int ni = 0; ni < 2; ++ni) {
            int gc = col0 + wc * 32 + ni * 16 + lr;
            float bg_ = biasg[gc], bu_ = biasu[gc];
#pragma unroll
            for (int r = 0; r < 4; ++r) {
                int gr = row0 + wr * 128 + mi * 16 + quad * 4 + r;
                float g = ag[mi][ni][r] + bg_;
                float u = au[mi][ni][r] + bu_;
                float v = 0.5f * g * (1.0f + erff(g * 0.70710678118654752f)) * u;
                C[(size_t)gr * FFF + gc] = __float2bfloat16(v);
            }
        }
    }
}

// ---------------------------------------------------------------------------
// prep_v: vb bf16 (MROWS,64) -> vtb bf16 (BB,64,SS) transposed per batch.
// ---------------------------------------------------------------------------
__global__ __launch_bounds__(256) void prep_v_kernel(const bf16* __restrict__ vb,
                                                     bf16* __restrict__ vtb) {
    __shared__ short t[64][65];
    int s0 = blockIdx.x * 64, b = blockIdx.y;
    int tid = threadIdx.x;
    const short* vs = (const short*)vb;
    short* vd = (short*)vtb;
    for (int i = tid; i < 4096; i += 256) {
        int s = i >> 6, d = i & 63;
        t[d][s] = vs[((size_t)(b * SS + s0 + s)) * 64 + d];
    }
    __syncthreads();
    for (int i = tid; i < 4096; i += 256) {
        int d = i >> 6, sl = i & 63;
        vd[((size_t)(b * 64 + d)) * SS + s0 + sl] = t[d][sl];
    }
}

// ---------------------------------------------------------------------------
// MFMA flash attention v6: fixed-shift softmax + k-split-2 (unchanged math)
// with LDS-staged, double-buffered K/V tiles. XOR-swizzled (both-sides).
// ---------------------------------------------------------------------------
#define PST 68
#define SM_SHIFT 6.0f

__global__ __launch_bounds__(256, 3) void attn_mfma_kernel(
        const bf16* __restrict__ q, const bf16* __restrict__ kb,
        const bf16* __restrict__ vt,
        float* __restrict__ O0p, float* __restrict__ O1p,
        float* __restrict__ l0p, float* __restrict__ l1p) {
    __shared__ short Kb_s[2][64 * 64];
    __shared__ short Vb_s[2][64 * 64];
    __shared__ short Ps[4][16 * PST];

    int h = blockIdx.y, b = blockIdx.z;
    int px = blockIdx.x >> 1, half = blockIdx.x & 1;
    int tid = threadIdx.x, w = tid >> 6, lane = tid & 63;
    int lr = lane & 15, quad = lane >> 4;
    int rsw = lane & 7;                 // read-side swizzle: row&7 == lr&7

    float* __restrict__ Op = half ? O1p : O0p;
    float* __restrict__ lp = half ? l1p : l0p;

    const bf16* kbB = kb + (size_t)b * SS * 64;
    const bf16* vtB = vt + (size_t)b * 64 * SS;

    int st_sub = lane >> 3;
    int st_col = ((lane & 7) ^ st_sub) << 3;      // element offset within row

    auto stage_tile = [&](int nxt, int j0s) {
#pragma unroll
        for (int i = 0; i < 2; ++i) {
            int rr = i * 32 + w * 8 + st_sub;
            __builtin_amdgcn_global_load_lds(
                (gas_t)(kbB + (size_t)(j0s + rr) * 64 + st_col),
                (las_t)&Kb_s[nxt][(i * 256 + w * 64) * 8], 16, 0, 0);
            __builtin_amdgcn_global_load_lds(
                (gas_t)(vtB + (size_t)rr * SS + j0s + st_col),
                (las_t)&Vb_s[nxt][(i * 256 + w * 64) * 8], 16, 0, 0);
        }
    };

    for (int pass = 0; pass < 2; ++pass) {
        int qt = (pass == 0) ? px : (SS / 64 - 1 - px);
        int q0 = qt * 64;

        const bf16* qrow = q + ((size_t)(b * SS + q0 + w * 16 + lr)) * (HH * HD) + h * HD;
        short8 qf0 = *(const short8*)(qrow + quad * 8);
        short8 qf1 = *(const short8*)(qrow + 32 + quad * 8);

        int n  = qt + 1;            // total k-tiles for this q-tile
        int n0 = (n + 1) >> 1;      // half 0 takes [0,n0), half 1 takes [n0,n)
        int tlo = half ? n0 : 0;
        int thi = half ? n  : n0;

        floatx4 O[4];
#pragma unroll
        for (int ni = 0; ni < 4; ++ni) O[ni] = (floatx4){0.f, 0.f, 0.f, 0.f};
        float lrow[4] = {0.f, 0.f, 0.f, 0.f};

        int cur = 0;
        if (tlo < thi) stage_tile(0, tlo * 64);
        __syncthreads();

        for (int t = tlo; t < thi; ++t) {
            // stage next tile into the other buffer (overlaps this compute)
            if (t + 1 < thi) stage_tile(cur ^ 1, (t + 1) * 64);

            int j0 = t * 64;

            // S = Q @ K^T   (K fragments from swizzled LDS)
            floatx4 S[4];
#pragma unroll
            for (int ni = 0; ni < 4; ++ni) S[ni] = (floatx4){0.f, 0.f, 0.f, 0.f};
#pragma unroll
            for (int ni = 0; ni < 4; ++ni) {
                const short* Kc = &Kb_s[cur][(ni * 16 + lr) * 64];
                short8 b0 = *(const short8*)&Kc[(quad ^ rsw) * 8];
                short8 b1 = *(const short8*)&Kc[((quad ^ rsw) ^ 4) * 8];
                S[ni] = __builtin_amdgcn_mfma_f32_16x16x32_bf16(qf0, b0, S[ni], 0, 0, 0);
                S[ni] = __builtin_amdgcn_mfma_f32_16x16x32_bf16(qf1, b1, S[ni], 0, 0, 0);
            }

            // V fragments (swizzled LDS), issued early to overlap exp + pack
            short8 vf[8];
#pragma unroll
            for (int ni = 0; ni < 4; ++ni) {
                const short* Vc = &Vb_s[cur][(ni * 16 + lr) * 64];
                vf[2 * ni]     = *(const short8*)&Vc[(quad ^ rsw) * 8];
                vf[2 * ni + 1] = *(const short8*)&Vc[((quad ^ rsw) ^ 4) * 8];
            }

            // causal mask on diagonal tile
            if (t == qt) {
                int rowg = q0 + w * 16 + quad * 4;
#pragma unroll
                for (int ni = 0; ni < 4; ++ni) {
                    int colg = j0 + ni * 16 + lr;
#pragma unroll
                    for (int r = 0; r < 4; ++r)
                        if (colg > rowg + r) S[ni][r] = -3.0e38f;
                }
            }

            // fixed-shift exp; accumulate per-lane row sums (no cross-lane ops)
#pragma unroll
            for (int ni = 0; ni < 4; ++ni)
#pragma unroll
                for (int r = 0; r < 4; ++r)
                    S[ni][r] = __expf(S[ni][r] - SM_SHIFT);
#pragma unroll
            for (int r = 0; r < 4; ++r)
                lrow[r] += S[0][r] + S[1][r] + S[2][r] + S[3][r];

            // pack P (bf16) to wave-private LDS in C-layout
#pragma unroll
            for (int ni = 0; ni < 4; ++ni)
#pragma unroll
                for (int r = 0; r < 4; ++r) {
                    bf16 pb = __float2bfloat16(S[ni][r]);
                    Ps[w][(quad * 4 + r) * PST + ni * 16 + lr] = *(short*)&pb;
                }
            short4v a0 = *(const short4v*)&Ps[w][lr * PST + quad * 8];
            short4v a1 = *(const short4v*)&Ps[w][lr * PST + quad * 8 + 4];
            short4v a2 = *(const short4v*)&Ps[w][lr * PST + 32 + quad * 8];
            short4v a3 = *(const short4v*)&Ps[w][lr * PST + 32 + quad * 8 + 4];
            short8 p0 = __builtin_shufflevector(a0, a1, 0, 1, 2, 3, 4, 5, 6, 7);
            short8 p1 = __builtin_shufflevector(a2, a3, 0, 1, 2, 3, 4, 5, 6, 7);

            // O += P @ V
#pragma unroll
            for (int ni = 0; ni < 4; ++ni) {
                O[ni] = __builtin_amdgcn_mfma_f32_16x16x32_bf16(p0, vf[2 * ni], O[ni], 0, 0, 0);
                O[ni] = __builtin_amdgcn_mfma_f32_16x16x32_bf16(p1, vf[2 * ni + 1], O[ni], 0, 0, 0);
            }

            // drains next-tile staging + ensures all waves done with cur
            __syncthreads();
            cur ^= 1;
        }

        // deferred row-sum reduction over the quad's 16 lanes (once per pass)
#pragma unroll
        for (int r = 0; r < 4; ++r) {
            float l = lrow[r];
            for (int off = 1; off < 16; off <<= 1) l += __shfl_xor(l, off, 64);
            lrow[r] = l;
        }

        // write unnormalized partials (zeros when this half's range is empty)
#pragma unroll
        for (int ni = 0; ni < 4; ++ni) {
            int gc = h * 64 + ni * 16 + lr;
#pragma unroll
            for (int r = 0; r < 4; ++r) {
                int gr = b * SS + q0 + w * 16 + quad * 4 + r;
                Op[(size_t)gr * (HH * HD) + gc] = O[ni][r];
            }
        }
        if (lr == 0) {
#pragma unroll
            for (int r = 0; r < 4; ++r) {
                int gr = b * SS + q0 + w * 16 + quad * 4 + r;
                lp[(size_t)gr * HH + h] = lrow[r];
            }
        }
    }
}

// ---------------------------------------------------------------------------
// Combine the two key-range halves: ao = (O0+O1)/(l0+l1), bf16 out.
// ---------------------------------------------------------------------------
__global__ __launch_bounds__(256) void attn_combine_kernel(
        const float* __restrict__ O0p, const float* __restrict__ O1p,
        const float* __restrict__ l0p, const float* __restrict__ l1p,
        bf16* __restrict__ o) {
    int idx = blockIdx.x * 256 + threadIdx.x;   // < MROWS*1024/4
    int d4  = idx & 15;
    int hh  = (idx >> 4) & 15;
    int row = idx >> 8;
    float l = l0p[row * HH + hh] + l1p[row * HH + hh];
    float inv = 1.0f / l;
    size_t base = (size_t)row * (HH * HD) + hh * 64 + d4 * 4;
    float4 a = *(const float4*)(O0p + base);
    float4 c = *(const float4*)(O1p + base);
    short4v o4;
    {
        bf16 v0 = __float2bfloat16((a.x + c.x) * inv);
        bf16 v1 = __float2bfloat16((a.y + c.y) * inv);
        bf16 v2 = __float2bfloat16((a.z + c.z) * inv);
        bf16 v3 = __float2bfloat16((a.w + c.w) * inv);
        o4[0] = *(short*)&v0; o4[1] = *(short*)&v1;
        o4[2] = *(short*)&v2; o4[3] = *(short*)&v3;
    }
    *(short4v*)(o + base) = o4;
}

// ---------------------------------------------------------------------------
// Launch (12 dispatches). Workspace (byte offsets, high-water 87 MB):
//   qbf @0 (8 MB, dead after attn; wgT reuses @0) | wuT @8M
//   x2 @16M (fp32 16 MB, written at wo; Opart0 borrows @16M during attn)
//   h1b/h2b @32M (8 MB) | vb @40M (bf16 0.5 MB)
//   ao @42M (8 MB, dead after wo; wdT reuses)
//   gg @50M (32 MB; pre-FFN its body hosts kbf @50M, vtb @50.5M, Opart1 @51M,
//            lparts @67M, rope tables @70M — all dead before gg is written)
//   wqkvT @82M (2.25 MB) | bqkv @84.5M | woT @85M (2 MB)
// ---------------------------------------------------------------------------
#define MB (1024ull * 1024ull)

extern "C" void kernel_launch(void* const* d_in, const int* in_sizes, int n_in,
                              void* d_out, int out_size, void* d_ws, size_t ws_size,
                              hipStream_t stream) {
    const float* x  = (const float*)d_in[0];
    const float* wq = (const float*)d_in[1];
    const float* bq = (const float*)d_in[2];
    const float* wk = (const float*)d_in[3];
    const float* bk = (const float*)d_in[4];
    const float* wv = (const float*)d_in[5];
    const float* bv = (const float*)d_in[6];
    const float* wo = (const float*)d_in[7];
    const float* bo = (const float*)d_in[8];
    const float* wg = (const float*)d_in[9];
    const float* bg = (const float*)d_in[10];
    const float* wu = (const float*)d_in[11];
    const float* bu = (const float*)d_in[12];
    const float* wd = (const float*)d_in[13];
    const float* bd = (const float*)d_in[14];
    const float* g1 = (const float*)d_in[15];
    const float* g2 = (const float*)d_in[16];
    float* out = (float*)d_out;

    char* ws = (char*)d_ws;
    bf16*  qbf   = (bf16*)(ws);
    bf16*  wuT   = (bf16*)(ws + 8 * MB);
    float* x2    = (float*)(ws + 16 * MB);
    bf16*  h1b   = (bf16*)(ws + 32 * MB);
    bf16*  vb    = (bf16*)(ws + 40 * MB);
    bf16*  ao    = (bf16*)(ws + 42 * MB);
    bf16*  gg    = (bf16*)(ws + 50 * MB);
    bf16*  kbf   = (bf16*)(ws + 50 * MB);              // over gg head (dead by FFN)
    bf16*  vtb   = (bf16*)(ws + 50 * MB + 512 * 1024);
    float* Opart0 = (float*)(ws + 16 * MB);            // over x2 (attn phase)
    float* Opart1 = (float*)(ws + 51 * MB);            // inside gg body
    float* lpart0 = (float*)(ws + 67 * MB);
    float* lpart1 = (float*)(ws + 67 * MB + 256 * 1024);
    float* ctab   = (float*)(ws + 70 * MB);
    float* stab   = (float*)(ws + 70 * MB + 256 * 1024);
    bf16*  wqkvT = (bf16*)(ws + 82 * MB);
    float* bqkv  = (float*)(ws + 84 * MB + 512 * 1024);
    bf16*  woT   = (bf16*)(ws + 85 * MB);
    bf16*  wgT   = (bf16*)(ws);                        // over qbf (dead after attn)
    bf16*  wdT   = (bf16*)(ws + 42 * MB);              // over ao (dead after wo GEMM)
    bf16*  h2b   = h1b;

    // 1. fused attention-side weight prep
    prep_weights_kernel<<<2437, 256, 0, stream>>>(
        wq, wk, wv, wo, bq, bk, bv, wqkvT, woT, bqkv, ctab, stab);

    // 2. h1 = rmsnorm(x, g1)
    rmsnorm_kernel<<<MROWS, 256, 0, stream>>>(x, g1, h1b, EE);

    // 3. fused QKV projection + RoPE epilogue -> qbf, kbf, vb
    gemm_qkv_kernel<<<dim3(NQKV / 128, MROWS / 128), 256, 0, stream>>>(
        h1b, wqkvT, bqkv, ctab, stab, qbf, kbf, vb, EE);

    // 4. v transpose -> vtb
    prep_v_kernel<<<dim3(SS / 64, BB), 256, 0, stream>>>(vb, vtb);

    // 5. attention partials (k-split x2) + combine -> ao [bf16]
    attn_mfma_kernel<<<dim3(2 * SS / 128, HH, BB), 256, 0, stream>>>(
        qbf, kbf, vtb, Opart0, Opart1, lpart0, lpart1);
    attn_combine_kernel<<<(MROWS * HH * HD / 4) / 256, 256, 0, stream>>>(
        Opart0, Opart1, lpart0, lpart1, ao);

    // 6. x2 = ao @ wo + bo + x  [fp32]
    gemm_n64_kernel<<<dim3(EE / 64, MROWS / 128), 256, 0, stream>>>(
        ao, woT, bo, x, x2, MROWS, EE, EE);

    // 7. h2 = rmsnorm(x2, g2)
    rmsnorm_kernel<<<MROWS, 256, 0, stream>>>(x2, g2, h2b, EE);

    // 8. fused FFN weight prep (qbf + ao now dead)
    ffn_weights_kernel<<<12288, 256, 0, stream>>>(wg, wu, wd, wgT, wuT, wdT);

    // 9. gg = gelu(h2@wg+bg) * (h2@wu+bu) — TWO row-half launches (~45us each)
    //    so the bench top-5 reveals the true #2 kernel next round.
    gemm_ffn_kernel<<<dim3(FFF / 128, MROWS / 512), 512, 0, stream>>>(
        h2b, wgT, wuT, bg, bu, gg, EE, 0);
    gemm_ffn_kernel<<<dim3(FFF / 128, MROWS / 512), 512, 0, stream>>>(
        h2b, wgT, wuT, bg, bu, gg, EE, MROWS / 512);

    // 10. out = gg @ wd + bd + x2  [fp32]
    gemm_n64_kernel<<<dim3(EE / 64, MROWS / 128), 256, 0, stream>>>(
        gg, wdT, bd, x2, out, MROWS, EE, FFF);
}

// Round 8
// 395.335 us; speedup vs baseline: 1.0610x; 1.0417x over previous
//
#include <hip/hip_runtime.h>
#include <hip/hip_bf16.h>
#include <math.h>

// Problem constants
#define BB 2
#define SS 2048
#define EE 1024
#define HH 16
#define HD 64
#define FFF 4096
#define MROWS (BB * SS)        // 4096
#define EPS_F 1.1920929e-7f
#define NQKV 1152              // 1024 q + 64 k + 64 v

typedef __hip_bfloat16 bf16;
typedef __attribute__((ext_vector_type(8))) short short8;
typedef __attribute__((ext_vector_type(4))) short short4v;
typedef __attribute__((ext_vector_type(4))) float floatx4;

typedef const __attribute__((address_space(1))) void* gas_t;
typedef __attribute__((address_space(3))) void* las_t;

// scheduling primitives for the 8-phase FFN kernel
#define BAR __builtin_amdgcn_s_barrier()
#define WLG do { asm volatile("s_waitcnt lgkmcnt(0)" ::: "memory"); \
                 __builtin_amdgcn_sched_barrier(0); } while (0)
#define VMC(N) asm volatile("s_waitcnt vmcnt(" #N ")" ::: "memory")

// ---------------------------------------------------------------------------
// RMSNorm: fp32 in, bf16 out. float4-vectorized (cols == 1024 == 256*4).
// ---------------------------------------------------------------------------
__global__ __launch_bounds__(256) void rmsnorm_kernel(const float* __restrict__ x,
                                                      const float* __restrict__ g,
                                                      bf16* __restrict__ out,
                                                      int cols) {
    int row = blockIdx.x, tid = threadIdx.x;
    const float4* xr = (const float4*)(x + (size_t)row * cols);
    float4 v = xr[tid];
    float ss = v.x * v.x + v.y * v.y + v.z * v.z + v.w * v.w;
    for (int off = 32; off > 0; off >>= 1) ss += __shfl_xor(ss, off, 64);
    __shared__ float red[4];
    int wave = tid >> 6;
    if ((tid & 63) == 0) red[wave] = ss;
    __syncthreads();
    float tot = red[0] + red[1] + red[2] + red[3];
    float rs = rsqrtf(tot / (float)cols + EPS_F);
    float4 gv = ((const float4*)g)[tid];
    short4v o;
    {
        bf16 b0 = __float2bfloat16(v.x * rs * gv.x);
        bf16 b1 = __float2bfloat16(v.y * rs * gv.y);
        bf16 b2 = __float2bfloat16(v.z * rs * gv.z);
        bf16 b3 = __float2bfloat16(v.w * rs * gv.w);
        o[0] = *(short*)&b0; o[1] = *(short*)&b1;
        o[2] = *(short*)&b2; o[3] = *(short*)&b3;
    }
    *(short4v*)(out + (size_t)row * cols + tid * 4) = o;
}

// ---------------------------------------------------------------------------
// 32x32 transpose+cast tile body (shared by the two fused weight-prep kernels)
// ---------------------------------------------------------------------------
__device__ __forceinline__ void transpose_tile32(const float* __restrict__ W,
                                                 bf16* __restrict__ Wt,
                                                 int K, int N, int bx, int by,
                                                 int tid, float (*t)[33]) {
    int n0 = bx * 32, k0 = by * 32;
    int tx = tid & 31, ty = tid >> 5;   // ty 0..7
#pragma unroll
    for (int i = 0; i < 4; ++i) {
        int kk = ty + i * 8;
        t[kk][tx] = W[(size_t)(k0 + kk) * N + n0 + tx];
    }
    __syncthreads();
#pragma unroll
    for (int i = 0; i < 4; ++i) {
        int nn = ty + i * 8;
        Wt[(size_t)(n0 + nn) * K + k0 + tx] = __float2bfloat16(t[tx][nn]);
    }
}

// ---------------------------------------------------------------------------
// Fused attention-side prep (1 launch):
//   wq/wk/wv/wo transposes + [bq|bk|bv] pack + RoPE cos/sin tables.
// Block ranges: [0,1024) wq | [1024,1088) wk | [1088,1152) wv |
//               [1152,2176) wo | [2176,2432) rope table | [2432,2437) pack.
// ---------------------------------------------------------------------------
__global__ __launch_bounds__(256) void prep_weights_kernel(
        const float* __restrict__ wq, const float* __restrict__ wk,
        const float* __restrict__ wv, const float* __restrict__ wo,
        const float* __restrict__ bq, const float* __restrict__ bk,
        const float* __restrict__ bv,
        bf16* __restrict__ wqkvT, bf16* __restrict__ woT,
        float* __restrict__ bqkv, float* __restrict__ ct, float* __restrict__ st) {
    __shared__ float t[32][33];
    int bid = blockIdx.x, tid = threadIdx.x;
    if (bid < 1024) {
        transpose_tile32(wq, wqkvT, EE, EE, bid & 31, bid >> 5, tid, t);
    } else if (bid < 1088) {
        int b2 = bid - 1024;
        transpose_tile32(wk, wqkvT + (size_t)1024 * EE, EE, HD, b2 & 1, b2 >> 1, tid, t);
    } else if (bid < 1152) {
        int b2 = bid - 1088;
        transpose_tile32(wv, wqkvT + (size_t)1088 * EE, EE, HD, b2 & 1, b2 >> 1, tid, t);
    } else if (bid < 2176) {
        int b2 = bid - 1152;
        transpose_tile32(wo, woT, EE, EE, b2 & 31, b2 >> 5, tid, t);
    } else if (bid < 2432) {
        int idx = (bid - 2176) * 256 + tid;       // SS*32 = 65536 entries
        int i = idx & 31, s = idx >> 5;
        float inv = powf(10000.0f, -(float)i / 32.0f);
        float ang = (float)s * inv;
        ct[idx] = cosf(ang);
        st[idx] = sinf(ang);
    } else {
        int tt = (bid - 2432) * 256 + tid;
        if (tt < NQKV) {
            float v;
            if (tt < 1024)      v = bq[tt];
            else if (tt < 1088) v = bk[tt - 1024];
            else                v = bv[tt - 1088];
            bqkv[tt] = v;
        }
    }
}

// ---------------------------------------------------------------------------
// Fused FFN weight prep (1 launch): wg/wu/wd transposes.
// [0,4096) wg | [4096,8192) wu | [8192,12288) wd.
// ---------------------------------------------------------------------------
__global__ __launch_bounds__(256) void ffn_weights_kernel(
        const float* __restrict__ wg, const float* __restrict__ wu,
        const float* __restrict__ wd,
        bf16* __restrict__ wgT, bf16* __restrict__ wuT, bf16* __restrict__ wdT) {
    __shared__ float t[32][33];
    int bid = blockIdx.x, tid = threadIdx.x;
    if (bid < 4096) {
        transpose_tile32(wg, wgT, EE, FFF, bid & 127, bid >> 7, tid, t);
    } else if (bid < 8192) {
        int b2 = bid - 4096;
        transpose_tile32(wu, wuT, EE, FFF, b2 & 127, b2 >> 7, tid, t);
    } else {
        int b2 = bid - 8192;
        transpose_tile32(wd, wdT, FFF, EE, b2 & 31, b2 >> 5, tid, t);
    }
}

// ---------------------------------------------------------------------------
// Fused QKV GEMM + RoPE epilogue, now with LDS chunk-XOR swizzle.
// Round-7 counters showed 128B LDS rows (GK=64 shorts) = 32-bank stride ->
// per-16-lane read group all lanes hit one 16B chunk column (~8x serialize).
// Fix (rule #21): staged source chunk pre-swizzled ((lane&7)^(lane>>3)),
// reads use chunk ((ks/8+lq)^(lr&7)) -> 8 bank-groups x 2 lanes = free.
// Fragment VALUES identical -> bit-identical output.
// ---------------------------------------------------------------------------
#define GK 64

__global__ __launch_bounds__(256) void gemm_qkv_kernel(
        const bf16* __restrict__ A, const bf16* __restrict__ Bt,
        const float* __restrict__ bias,
        const float* __restrict__ ct, const float* __restrict__ st,
        bf16* __restrict__ qout, bf16* __restrict__ kout,
        bf16* __restrict__ vout, int K) {
    __shared__ short As[128 * GK];
    __shared__ short Bs[128 * GK];
    int tid = threadIdx.x;
    int wave = tid >> 6, lane = tid & 63;
    int wm = (wave >> 1) * 64, wn = (wave & 1) * 64;
    int row0 = blockIdx.y * 128, col0 = blockIdx.x * 128;
    int lr = lane & 15, lq = lane >> 4;
    int rsw = lr & 7;                     // read-side swizzle key (row&7)

    int srow = wave * 32 + (lane >> 3);
    int scol = ((lane & 7) ^ (lane >> 3)) * 8;   // pre-swizzled source chunk
    const bf16* Abase = A + (size_t)(row0 + srow) * K + scol;
    const bf16* Bbase = Bt + (size_t)(col0 + srow) * K + scol;

    floatx4 acc[4][4];
#pragma unroll
    for (int mi = 0; mi < 4; ++mi)
#pragma unroll
        for (int ni = 0; ni < 4; ++ni)
            acc[mi][ni] = (floatx4){0.f, 0.f, 0.f, 0.f};

    for (int k0 = 0; k0 < K; k0 += GK) {
        __syncthreads();
#pragma unroll
        for (int c = 0; c < 4; ++c) {
            __builtin_amdgcn_global_load_lds(
                (gas_t)(Abase + (size_t)(c * 8) * K + k0),
                (las_t)&As[(wave * 32 + c * 8) * GK], 16, 0, 0);
            __builtin_amdgcn_global_load_lds(
                (gas_t)(Bbase + (size_t)(c * 8) * K + k0),
                (las_t)&Bs[(wave * 32 + c * 8) * GK], 16, 0, 0);
        }
        __syncthreads();
#pragma unroll
        for (int ks = 0; ks < GK; ks += 32) {
            int cswz = (((ks >> 3) + lq) ^ rsw) * 8;   // swizzled chunk offset
            short8 af[4], bfr[4];
#pragma unroll
            for (int mi = 0; mi < 4; ++mi)
                af[mi] = *(const short8*)&As[(wm + mi * 16 + lr) * GK + cswz];
#pragma unroll
            for (int ni = 0; ni < 4; ++ni)
                bfr[ni] = *(const short8*)&Bs[(wn + ni * 16 + lr) * GK + cswz];
#pragma unroll
            for (int mi = 0; mi < 4; ++mi)
#pragma unroll
                for (int ni = 0; ni < 4; ++ni)
                    acc[mi][ni] = __builtin_amdgcn_mfma_f32_16x16x32_bf16(
                        af[mi], bfr[ni], acc[mi][ni], 0, 0, 0);
        }
    }

    int hcol = col0 + wn;                 // 64-aligned head-span base
    if (hcol < 1088) {                    // q (hcol<1024) or k (hcol==1024)
        bool isQ = hcol < 1024;
#pragma unroll
        for (int mi = 0; mi < 4; ++mi) {
#pragma unroll
            for (int ni = 0; ni < 2; ++ni) {
                int i = ni * 16 + lr;
                float b1 = bias[hcol + i];
                float b2 = bias[hcol + i + 32];
#pragma unroll
                for (int r = 0; r < 4; ++r) {
                    int gr = row0 + wm + mi * 16 + lq * 4 + r;
                    int s = gr & (SS - 1);
                    float c  = ct[s * 32 + i];
                    float sn = st[s * 32 + i];
                    float t1 = acc[mi][ni][r] + b1;
                    float t2 = acc[mi][ni + 2][r] + b2;
                    float o1 = t1 * c - t2 * sn;
                    float o2 = t1 * sn + t2 * c;
                    if (isQ) {
                        qout[(size_t)gr * 1024 + hcol + i]      = __float2bfloat16(o1 * 0.125f);
                        qout[(size_t)gr * 1024 + hcol + i + 32] = __float2bfloat16(o2 * 0.125f);
                    } else {
                        kout[(size_t)gr * 64 + i]      = __float2bfloat16(o1);
                        kout[(size_t)gr * 64 + i + 32] = __float2bfloat16(o2);
                    }
                }
            }
        }
    } else {                              // v: plain bias + cast
#pragma unroll
        for (int mi = 0; mi < 4; ++mi)
#pragma unroll
            for (int ni = 0; ni < 4; ++ni) {
                int vcol = ni * 16 + lr;
                float bv_ = bias[1088 + vcol];
#pragma unroll
                for (int r = 0; r < 4; ++r) {
                    int gr = row0 + wm + mi * 16 + lq * 4 + r;
                    vout[(size_t)gr * 64 + vcol] = __float2bfloat16(acc[mi][ni][r] + bv_);
                }
            }
    }
}

// ---------------------------------------------------------------------------
// GEMM 128x64 tiles (wo, wd): C = A@Bt^T + bias + aux. Round-7 diagnosis:
// 18.9M LDS bank-conflict cycles (~40% of kernel) + 143MB fetch (2.6x ideal,
// A-row-panels refetched by all 8 XCDs). Fixes:
//  (a) chunk-XOR swizzle (as gemm_qkv above) -> conflict-free reads;
//  (b) XCD-aware block swizzle: swz=(id&7)*64+(id>>3) (512%8==0, bijective)
//      -> each XCD owns 4 contiguous row-panels (4MB A set fits its L2).
// Bit-identical numerics (same fragments, same MFMA order).
// ---------------------------------------------------------------------------
__global__ __launch_bounds__(256) void gemm_n64_kernel(
        const bf16* __restrict__ A, const bf16* __restrict__ Bt,
        const float* __restrict__ bias, const float* __restrict__ aux,
        float* __restrict__ C, int M, int N, int K) {
    __shared__ short As[128 * GK];
    __shared__ short Bs[64 * GK];
    int tid = threadIdx.x;
    int wave = tid >> 6, lane = tid & 63;
    int wm = wave * 32;

    // XCD-aware remap of the (16 x 32) grid
    int nwg = gridDim.x * gridDim.y;                 // 512
    int id  = blockIdx.y * gridDim.x + blockIdx.x;
    int swz = (id & 7) * (nwg >> 3) + (id >> 3);
    int bx = swz % gridDim.x, by = swz / gridDim.x;
    int row0 = by * 128, col0 = bx * 64;

    int lr = lane & 15, lq = lane >> 4;
    int rsw = lr & 7;

    int srow = (lane >> 3);
    int scol = ((lane & 7) ^ (lane >> 3)) * 8;       // pre-swizzled source
    const bf16* Abase = A + (size_t)(row0 + wave * 32 + srow) * K + scol;
    const bf16* Bbase = Bt + (size_t)(col0 + wave * 16 + srow) * K + scol;

    floatx4 acc[2][4];
#pragma unroll
    for (int mi = 0; mi < 2; ++mi)
#pragma unroll
        for (int ni = 0; ni < 4; ++ni)
            acc[mi][ni] = (floatx4){0.f, 0.f, 0.f, 0.f};

    for (int k0 = 0; k0 < K; k0 += GK) {
        __syncthreads();
#pragma unroll
        for (int c = 0; c < 4; ++c)
            __builtin_amdgcn_global_load_lds(
                (gas_t)(Abase + (size_t)(c * 8) * K + k0),
                (las_t)&As[(wave * 32 + c * 8) * GK], 16, 0, 0);
#pragma unroll
        for (int c = 0; c < 2; ++c)
            __builtin_amdgcn_global_load_lds(
                (gas_t)(Bbase + (size_t)(c * 8) * K + k0),
                (las_t)&Bs[(wave * 16 + c * 8) * GK], 16, 0, 0);
        __syncthreads();
#pragma unroll
        for (int ks = 0; ks < GK; ks += 32) {
            int cswz = (((ks >> 3) + lq) ^ rsw) * 8;
            short8 af[2], bfr[4];
#pragma unroll
            for (int mi = 0; mi < 2; ++mi)
                af[mi] = *(const short8*)&As[(wm + mi * 16 + lr) * GK + cswz];
#pragma unroll
            for (int ni = 0; ni < 4; ++ni)
                bfr[ni] = *(const short8*)&Bs[(ni * 16 + lr) * GK + cswz];
#pragma unroll
            for (int mi = 0; mi < 2; ++mi)
#pragma unroll
                for (int ni = 0; ni < 4; ++ni)
                    acc[mi][ni] = __builtin_amdgcn_mfma_f32_16x16x32_bf16(
                        af[mi], bfr[ni], acc[mi][ni], 0, 0, 0);
        }
    }

#pragma unroll
    for (int mi = 0; mi < 2; ++mi) {
#pragma unroll
        for (int ni = 0; ni < 4; ++ni) {
            int gc = col0 + ni * 16 + lr;
            float bv = bias[gc];
#pragma unroll
            for (int r = 0; r < 4; ++r) {
                int gr = row0 + wm + mi * 16 + lq * 4 + r;
                size_t idx = (size_t)gr * N + gc;
                C[idx] = acc[mi][ni][r] + bv + aux[idx];
            }
        }
    }
}

// ---------------------------------------------------------------------------
// Fused FFN GEMM, 8-phase schedule (T2+T3+T4+T5), swizzled + B-reg-reuse.
// Two row-half launches (instrumentation: keeps top-5 informative).
// ---------------------------------------------------------------------------
#define FFN_RD_A(KH, MH) \
    { const short* Ap = &Ab[buf][KH][0]; \
      af[0] = *(const short8*)&Ap[(wr * 128 + ((MH) * 4 + 0) * 16 + lr) * 32 + cs8]; \
      af[1] = *(const short8*)&Ap[(wr * 128 + ((MH) * 4 + 1) * 16 + lr) * 32 + cs8]; \
      af[2] = *(const short8*)&Ap[(wr * 128 + ((MH) * 4 + 2) * 16 + lr) * 32 + cs8]; \
      af[3] = *(const short8*)&Ap[(wr * 128 + ((MH) * 4 + 3) * 16 + lr) * 32 + cs8]; }

#define FFN_RD_B(KH) \
    { const short* Bp = &Bb[buf][KH][0]; \
      gf[0] = *(const short8*)&Bp[(wc * 32 + lr) * 32 + cs8]; \
      gf[1] = *(const short8*)&Bp[(wc * 32 + 16 + lr) * 32 + cs8]; \
      uf[0] = *(const short8*)&Bp[4096 + (wc * 32 + lr) * 32 + cs8]; \
      uf[1] = *(const short8*)&Bp[4096 + (wc * 32 + 16 + lr) * 32 + cs8]; }

#define FFN_MM(MH) \
    __builtin_amdgcn_s_setprio(1); \
    { _Pragma("unroll") for (int mi = 0; mi < 4; ++mi) { \
        ag[(MH) * 4 + mi][0] = __builtin_amdgcn_mfma_f32_16x16x32_bf16(af[mi], gf[0], ag[(MH) * 4 + mi][0], 0, 0, 0); \
        ag[(MH) * 4 + mi][1] = __builtin_amdgcn_mfma_f32_16x16x32_bf16(af[mi], gf[1], ag[(MH) * 4 + mi][1], 0, 0, 0); \
        au[(MH) * 4 + mi][0] = __builtin_amdgcn_mfma_f32_16x16x32_bf16(af[mi], uf[0], au[(MH) * 4 + mi][0], 0, 0, 0); \
        au[(MH) * 4 + mi][1] = __builtin_amdgcn_mfma_f32_16x16x32_bf16(af[mi], uf[1], au[(MH) * 4 + mi][1], 0, 0, 0); } } \
    __builtin_amdgcn_s_setprio(0);

__global__ __launch_bounds__(512, 2) void gemm_ffn_kernel(
        const bf16* __restrict__ A, const bf16* __restrict__ Bg,
        const bf16* __restrict__ Bu, const float* __restrict__ biasg,
        const float* __restrict__ biasu, bf16* __restrict__ C, int K, int rowoff) {
    __shared__ short Ab[2][2][8192];   // [buf][khalf][256 rows x 32 cols, swz]
    __shared__ short Bb[2][2][8192];   // [buf][khalf][G 128 | U 128, swz]

    const int tid = threadIdx.x;
    const int w = tid >> 6, lane = tid & 63;
    const int wr = w >> 2, wc = w & 3;           // 2M x 4N waves
    const int lr = lane & 15, quad = lane >> 4;
    const int row0 = (blockIdx.y + rowoff) * 256, col0 = blockIdx.x * 128;
    const int NT = K >> 6;                       // 16 K-tiles
    const int cs8 = (quad ^ ((lr >> 1) & 3)) * 8;   // swizzled read chunk

    const int sr = tid >> 2;                     // staging row 0..127
    const int scs = (((tid & 3) ^ ((tid >> 3) & 3))) * 8;

    auto stageA = [&](short* dst, int kcol) {
        __builtin_amdgcn_global_load_lds(
            (gas_t)(A + (size_t)(row0 + sr) * K + kcol + scs),
            (las_t)(dst + tid * 8), 16, 0, 0);
        __builtin_amdgcn_global_load_lds(
            (gas_t)(A + (size_t)(row0 + 128 + sr) * K + kcol + scs),
            (las_t)(dst + 4096 + tid * 8), 16, 0, 0);
    };
    auto stageB = [&](short* dst, int kcol) {
        __builtin_amdgcn_global_load_lds(
            (gas_t)(Bg + (size_t)(col0 + sr) * K + kcol + scs),
            (las_t)(dst + tid * 8), 16, 0, 0);
        __builtin_amdgcn_global_load_lds(
            (gas_t)(Bu + (size_t)(col0 + sr) * K + kcol + scs),
            (las_t)(dst + 4096 + tid * 8), 16, 0, 0);
    };

    floatx4 ag[8][2], au[8][2];
#pragma unroll
    for (int mi = 0; mi < 8; ++mi)
#pragma unroll
        for (int ni = 0; ni < 2; ++ni) {
            ag[mi][ni] = (floatx4){0.f, 0.f, 0.f, 0.f};
            au[mi][ni] = (floatx4){0.f, 0.f, 0.f, 0.f};
        }

    // prologue: 6 half-tiles; drain to 8 outstanding (t0A0,t0B0 landed)
    stageA(&Ab[0][0][0], 0);
    stageB(&Bb[0][0][0], 0);
    stageA(&Ab[0][1][0], 32);
    stageB(&Bb[0][1][0], 32);
    stageA(&Ab[1][0][0], 64);
    stageB(&Bb[1][0][0], 64);
    VMC(8);
    BAR;

    for (int k = 0; k < NT; ++k) {
        const int buf = k & 1;
        short8 gf[2], uf[2];
        {   // phase 1: kh0, mh0 | read af + gf/uf(kh0) | stage tile k+1 A-k1
            short8 af[4];
            FFN_RD_A(0, 0)
            FFN_RD_B(0)
            if (k + 1 < NT) stageA(&Ab[buf ^ 1][1][0], (k + 1) * 64 + 32);
            BAR; WLG;
            FFN_MM(0)
            BAR;
        }
        {   // phase 2: kh0, mh1 | af only (gf/uf in regs) | stage k+1 B-k1
            short8 af[4];
            FFN_RD_A(0, 1)
            if (k + 1 < NT) stageB(&Bb[buf ^ 1][1][0], (k + 1) * 64 + 32);
            BAR; WLG;
            FFN_MM(1)
            if (k < NT - 1) { VMC(8); } else { VMC(0); }
            BAR;
        }
        {   // phase 3: kh1, mh0 | read af + gf/uf(kh1) | stage k+2 A-k0
            short8 af[4];
            FFN_RD_A(1, 0)
            FFN_RD_B(1)
            if (k + 2 < NT) stageA(&Ab[buf][0][0], (k + 2) * 64);
            BAR; WLG;
            FFN_MM(0)
            BAR;
        }
        {   // phase 4: kh1, mh1 | af only | stage k+2 B-k0
            short8 af[4];
            FFN_RD_A(1, 1)
            if (k + 2 < NT) stageB(&Bb[buf][0][0], (k + 2) * 64);
            BAR; WLG;
            FFN_MM(1)
            if (k < NT - 2) { VMC(8); } else if (k == NT - 2) { VMC(4); }
            BAR;
        }
    }

#pragma unroll
    for (int mi = 0; mi < 8; ++mi) {
#pragma unroll
        for (int ni = 0; ni < 2; ++ni) {
            int gc = col0 + wc * 32 + ni * 16 + lr;
            float bg_ = biasg[gc], bu_ = biasu[gc];
#pragma unroll
            for (int r = 0; r < 4; ++r) {
                int gr = row0 + wr * 128 + mi * 16 + quad * 4 + r;
                float g = ag[mi][ni][r] + bg_;
                float u = au[mi][ni][r] + bu_;
                float v = 0.5f * g * (1.0f + erff(g * 0.70710678118654752f)) * u;
                C[(size_t)gr * FFF + gc] = __float2bfloat16(v);
            }
        }
    }
}

// ---------------------------------------------------------------------------
// prep_v: vb bf16 (MROWS,64) -> vtb bf16 (BB,64,SS) transposed per batch.
// ---------------------------------------------------------------------------
__global__ __launch_bounds__(256) void prep_v_kernel(const bf16* __restrict__ vb,
                                                     bf16* __restrict__ vtb) {
    __shared__ short t[64][65];
    int s0 = blockIdx.x * 64, b = blockIdx.y;
    int tid = threadIdx.x;
    const short* vs = (const short*)vb;
    short* vd = (short*)vtb;
    for (int i = tid; i < 4096; i += 256) {
        int s = i >> 6, d = i & 63;
        t[d][s] = vs[((size_t)(b * SS + s0 + s)) * 64 + d];
    }
    __syncthreads();
    for (int i = tid; i < 4096; i += 256) {
        int d = i >> 6, sl = i & 63;
        vd[((size_t)(b * 64 + d)) * SS + s0 + sl] = t[d][sl];
    }
}

// ---------------------------------------------------------------------------
// MFMA flash attention v6: fixed-shift softmax + k-split-2 (unchanged math)
// with LDS-staged, double-buffered K/V tiles. XOR-swizzled (both-sides).
// ---------------------------------------------------------------------------
#define PST 68
#define SM_SHIFT 6.0f

__global__ __launch_bounds__(256, 3) void attn_mfma_kernel(
        const bf16* __restrict__ q, const bf16* __restrict__ kb,
        const bf16* __restrict__ vt,
        float* __restrict__ O0p, float* __restrict__ O1p,
        float* __restrict__ l0p, float* __restrict__ l1p) {
    __shared__ short Kb_s[2][64 * 64];
    __shared__ short Vb_s[2][64 * 64];
    __shared__ short Ps[4][16 * PST];

    int h = blockIdx.y, b = blockIdx.z;
    int px = blockIdx.x >> 1, half = blockIdx.x & 1;
    int tid = threadIdx.x, w = tid >> 6, lane = tid & 63;
    int lr = lane & 15, quad = lane >> 4;
    int rsw = lane & 7;                 // read-side swizzle: row&7 == lr&7

    float* __restrict__ Op = half ? O1p : O0p;
    float* __restrict__ lp = half ? l1p : l0p;

    const bf16* kbB = kb + (size_t)b * SS * 64;
    const bf16* vtB = vt + (size_t)b * 64 * SS;

    int st_sub = lane >> 3;
    int st_col = ((lane & 7) ^ st_sub) << 3;      // element offset within row

    auto stage_tile = [&](int nxt, int j0s) {
#pragma unroll
        for (int i = 0; i < 2; ++i) {
            int rr = i * 32 + w * 8 + st_sub;
            __builtin_amdgcn_global_load_lds(
                (gas_t)(kbB + (size_t)(j0s + rr) * 64 + st_col),
                (las_t)&Kb_s[nxt][(i * 256 + w * 64) * 8], 16, 0, 0);
            __builtin_amdgcn_global_load_lds(
                (gas_t)(vtB + (size_t)rr * SS + j0s + st_col),
                (las_t)&Vb_s[nxt][(i * 256 + w * 64) * 8], 16, 0, 0);
        }
    };

    for (int pass = 0; pass < 2; ++pass) {
        int qt = (pass == 0) ? px : (SS / 64 - 1 - px);
        int q0 = qt * 64;

        const bf16* qrow = q + ((size_t)(b * SS + q0 + w * 16 + lr)) * (HH * HD) + h * HD;
        short8 qf0 = *(const short8*)(qrow + quad * 8);
        short8 qf1 = *(const short8*)(qrow + 32 + quad * 8);

        int n  = qt + 1;            // total k-tiles for this q-tile
        int n0 = (n + 1) >> 1;      // half 0 takes [0,n0), half 1 takes [n0,n)
        int tlo = half ? n0 : 0;
        int thi = half ? n  : n0;

        floatx4 O[4];
#pragma unroll
        for (int ni = 0; ni < 4; ++ni) O[ni] = (floatx4){0.f, 0.f, 0.f, 0.f};
        float lrow[4] = {0.f, 0.f, 0.f, 0.f};

        int cur = 0;
        if (tlo < thi) stage_tile(0, tlo * 64);
        __syncthreads();

        for (int t = tlo; t < thi; ++t) {
            // stage next tile into the other buffer (overlaps this compute)
            if (t + 1 < thi) stage_tile(cur ^ 1, (t + 1) * 64);

            int j0 = t * 64;

            // S = Q @ K^T   (K fragments from swizzled LDS)
            floatx4 S[4];
#pragma unroll
            for (int ni = 0; ni < 4; ++ni) S[ni] = (floatx4){0.f, 0.f, 0.f, 0.f};
#pragma unroll
            for (int ni = 0; ni < 4; ++ni) {
                const short* Kc = &Kb_s[cur][(ni * 16 + lr) * 64];
                short8 b0 = *(const short8*)&Kc[(quad ^ rsw) * 8];
                short8 b1 = *(const short8*)&Kc[((quad ^ rsw) ^ 4) * 8];
                S[ni] = __builtin_amdgcn_mfma_f32_16x16x32_bf16(qf0, b0, S[ni], 0, 0, 0);
                S[ni] = __builtin_amdgcn_mfma_f32_16x16x32_bf16(qf1, b1, S[ni], 0, 0, 0);
            }

            // V fragments (swizzled LDS), issued early to overlap exp + pack
            short8 vf[8];
#pragma unroll
            for (int ni = 0; ni < 4; ++ni) {
                const short* Vc = &Vb_s[cur][(ni * 16 + lr) * 64];
                vf[2 * ni]     = *(const short8*)&Vc[(quad ^ rsw) * 8];
                vf[2 * ni + 1] = *(const short8*)&Vc[((quad ^ rsw) ^ 4) * 8];
            }

            // causal mask on diagonal tile
            if (t == qt) {
                int rowg = q0 + w * 16 + quad * 4;
#pragma unroll
                for (int ni = 0; ni < 4; ++ni) {
                    int colg = j0 + ni * 16 + lr;
#pragma unroll
                    for (int r = 0; r < 4; ++r)
                        if (colg > rowg + r) S[ni][r] = -3.0e38f;
                }
            }

            // fixed-shift exp; accumulate per-lane row sums (no cross-lane ops)
#pragma unroll
            for (int ni = 0; ni < 4; ++ni)
#pragma unroll
                for (int r = 0; r < 4; ++r)
                    S[ni][r] = __expf(S[ni][r] - SM_SHIFT);
#pragma unroll
            for (int r = 0; r < 4; ++r)
                lrow[r] += S[0][r] + S[1][r] + S[2][r] + S[3][r];

            // pack P (bf16) to wave-private LDS in C-layout
#pragma unroll
            for (int ni = 0; ni < 4; ++ni)
#pragma unroll
                for (int r = 0; r < 4; ++r) {
                    bf16 pb = __float2bfloat16(S[ni][r]);
                    Ps[w][(quad * 4 + r) * PST + ni * 16 + lr] = *(short*)&pb;
                }
            short4v a0 = *(const short4v*)&Ps[w][lr * PST + quad * 8];
            short4v a1 = *(const short4v*)&Ps[w][lr * PST + quad * 8 + 4];
            short4v a2 = *(const short4v*)&Ps[w][lr * PST + 32 + quad * 8];
            short4v a3 = *(const short4v*)&Ps[w][lr * PST + 32 + quad * 8 + 4];
            short8 p0 = __builtin_shufflevector(a0, a1, 0, 1, 2, 3, 4, 5, 6, 7);
            short8 p1 = __builtin_shufflevector(a2, a3, 0, 1, 2, 3, 4, 5, 6, 7);

            // O += P @ V
#pragma unroll
            for (int ni = 0; ni < 4; ++ni) {
                O[ni] = __builtin_amdgcn_mfma_f32_16x16x32_bf16(p0, vf[2 * ni], O[ni], 0, 0, 0);
                O[ni] = __builtin_amdgcn_mfma_f32_16x16x32_bf16(p1, vf[2 * ni + 1], O[ni], 0, 0, 0);
            }

            // drains next-tile staging + ensures all waves done with cur
            __syncthreads();
            cur ^= 1;
        }

        // deferred row-sum reduction over the quad's 16 lanes (once per pass)
#pragma unroll
        for (int r = 0; r < 4; ++r) {
            float l = lrow[r];
            for (int off = 1; off < 16; off <<= 1) l += __shfl_xor(l, off, 64);
            lrow[r] = l;
        }

        // write unnormalized partials (zeros when this half's range is empty)
#pragma unroll
        for (int ni = 0; ni < 4; ++ni) {
            int gc = h * 64 + ni * 16 + lr;
#pragma unroll
            for (int r = 0; r < 4; ++r) {
                int gr = b * SS + q0 + w * 16 + quad * 4 + r;
                Op[(size_t)gr * (HH * HD) + gc] = O[ni][r];
            }
        }
        if (lr == 0) {
#pragma unroll
            for (int r = 0; r < 4; ++r) {
                int gr = b * SS + q0 + w * 16 + quad * 4 + r;
                lp[(size_t)gr * HH + h] = lrow[r];
            }
        }
    }
}

// ---------------------------------------------------------------------------
// Combine the two key-range halves: ao = (O0+O1)/(l0+l1), bf16 out.
// ---------------------------------------------------------------------------
__global__ __launch_bounds__(256) void attn_combine_kernel(
        const float* __restrict__ O0p, const float* __restrict__ O1p,
        const float* __restrict__ l0p, const float* __restrict__ l1p,
        bf16* __restrict__ o) {
    int idx = blockIdx.x * 256 + threadIdx.x;   // < MROWS*1024/4
    int d4  = idx & 15;
    int hh  = (idx >> 4) & 15;
    int row = idx >> 8;
    float l = l0p[row * HH + hh] + l1p[row * HH + hh];
    float inv = 1.0f / l;
    size_t base = (size_t)row * (HH * HD) + hh * 64 + d4 * 4;
    float4 a = *(const float4*)(O0p + base);
    float4 c = *(const float4*)(O1p + base);
    short4v o4;
    {
        bf16 v0 = __float2bfloat16((a.x + c.x) * inv);
        bf16 v1 = __float2bfloat16((a.y + c.y) * inv);
        bf16 v2 = __float2bfloat16((a.z + c.z) * inv);
        bf16 v3 = __float2bfloat16((a.w + c.w) * inv);
        o4[0] = *(short*)&v0; o4[1] = *(short*)&v1;
        o4[2] = *(short*)&v2; o4[3] = *(short*)&v3;
    }
    *(short4v*)(o + base) = o4;
}

// ---------------------------------------------------------------------------
// Launch (12 dispatches). Workspace (byte offsets, high-water 87 MB):
//   qbf @0 (8 MB, dead after attn; wgT reuses @0) | wuT @8M
//   x2 @16M (fp32 16 MB, written at wo; Opart0 borrows @16M during attn)
//   h1b/h2b @32M (8 MB) | vb @40M (bf16 0.5 MB)
//   ao @42M (8 MB, dead after wo; wdT reuses)
//   gg @50M (32 MB; pre-FFN its body hosts kbf @50M, vtb @50.5M, Opart1 @51M,
//            lparts @67M, rope tables @70M — all dead before gg is written)
//   wqkvT @82M (2.25 MB) | bqkv @84.5M | woT @85M (2 MB)
// ---------------------------------------------------------------------------
#define MB (1024ull * 1024ull)

extern "C" void kernel_launch(void* const* d_in, const int* in_sizes, int n_in,
                              void* d_out, int out_size, void* d_ws, size_t ws_size,
                              hipStream_t stream) {
    const float* x  = (const float*)d_in[0];
    const float* wq = (const float*)d_in[1];
    const float* bq = (const float*)d_in[2];
    const float* wk = (const float*)d_in[3];
    const float* bk = (const float*)d_in[4];
    const float* wv = (const float*)d_in[5];
    const float* bv = (const float*)d_in[6];
    const float* wo = (const float*)d_in[7];
    const float* bo = (const float*)d_in[8];
    const float* wg = (const float*)d_in[9];
    const float* bg = (const float*)d_in[10];
    const float* wu = (const float*)d_in[11];
    const float* bu = (const float*)d_in[12];
    const float* wd = (const float*)d_in[13];
    const float* bd = (const float*)d_in[14];
    const float* g1 = (const float*)d_in[15];
    const float* g2 = (const float*)d_in[16];
    float* out = (float*)d_out;

    char* ws = (char*)d_ws;
    bf16*  qbf   = (bf16*)(ws);
    bf16*  wuT   = (bf16*)(ws + 8 * MB);
    float* x2    = (float*)(ws + 16 * MB);
    bf16*  h1b   = (bf16*)(ws + 32 * MB);
    bf16*  vb    = (bf16*)(ws + 40 * MB);
    bf16*  ao    = (bf16*)(ws + 42 * MB);
    bf16*  gg    = (bf16*)(ws + 50 * MB);
    bf16*  kbf   = (bf16*)(ws + 50 * MB);              // over gg head (dead by FFN)
    bf16*  vtb   = (bf16*)(ws + 50 * MB + 512 * 1024);
    float* Opart0 = (float*)(ws + 16 * MB);            // over x2 (attn phase)
    float* Opart1 = (float*)(ws + 51 * MB);            // inside gg body
    float* lpart0 = (float*)(ws + 67 * MB);
    float* lpart1 = (float*)(ws + 67 * MB + 256 * 1024);
    float* ctab   = (float*)(ws + 70 * MB);
    float* stab   = (float*)(ws + 70 * MB + 256 * 1024);
    bf16*  wqkvT = (bf16*)(ws + 82 * MB);
    float* bqkv  = (float*)(ws + 84 * MB + 512 * 1024);
    bf16*  woT   = (bf16*)(ws + 85 * MB);
    bf16*  wgT   = (bf16*)(ws);                        // over qbf (dead after attn)
    bf16*  wdT   = (bf16*)(ws + 42 * MB);              // over ao (dead after wo GEMM)
    bf16*  h2b   = h1b;

    // 1. fused attention-side weight prep
    prep_weights_kernel<<<2437, 256, 0, stream>>>(
        wq, wk, wv, wo, bq, bk, bv, wqkvT, woT, bqkv, ctab, stab);

    // 2. h1 = rmsnorm(x, g1)
    rmsnorm_kernel<<<MROWS, 256, 0, stream>>>(x, g1, h1b, EE);

    // 3. fused QKV projection + RoPE epilogue -> qbf, kbf, vb  [LDS swizzled]
    gemm_qkv_kernel<<<dim3(NQKV / 128, MROWS / 128), 256, 0, stream>>>(
        h1b, wqkvT, bqkv, ctab, stab, qbf, kbf, vb, EE);

    // 4. v transpose -> vtb
    prep_v_kernel<<<dim3(SS / 64, BB), 256, 0, stream>>>(vb, vtb);

    // 5. attention partials (k-split x2) + combine -> ao [bf16]
    attn_mfma_kernel<<<dim3(2 * SS / 128, HH, BB), 256, 0, stream>>>(
        qbf, kbf, vtb, Opart0, Opart1, lpart0, lpart1);
    attn_combine_kernel<<<(MROWS * HH * HD / 4) / 256, 256, 0, stream>>>(
        Opart0, Opart1, lpart0, lpart1, ao);

    // 6. x2 = ao @ wo + bo + x  [LDS swizzle + XCD swizzle]
    gemm_n64_kernel<<<dim3(EE / 64, MROWS / 128), 256, 0, stream>>>(
        ao, woT, bo, x, x2, MROWS, EE, EE);

    // 7. h2 = rmsnorm(x2, g2)
    rmsnorm_kernel<<<MROWS, 256, 0, stream>>>(x2, g2, h2b, EE);

    // 8. fused FFN weight prep (qbf + ao now dead)
    ffn_weights_kernel<<<12288, 256, 0, stream>>>(wg, wu, wd, wgT, wuT, wdT);

    // 9. gg = gelu(h2@wg+bg) * (h2@wu+bu) — two row-half launches
    gemm_ffn_kernel<<<dim3(FFF / 128, MROWS / 512), 512, 0, stream>>>(
        h2b, wgT, wuT, bg, bu, gg, EE, 0);
    gemm_ffn_kernel<<<dim3(FFF / 128, MROWS / 512), 512, 0, stream>>>(
        h2b, wgT, wuT, bg, bu, gg, EE, MROWS / 512);

    // 10. out = gg @ wd + bd + x2  [LDS swizzle + XCD swizzle]
    gemm_n64_kernel<<<dim3(EE / 64, MROWS / 128), 256, 0, stream>>>(
        gg, wdT, bd, x2, out, MROWS, EE, FFF);
}

// Round 9
// 391.566 us; speedup vs baseline: 1.0712x; 1.0096x over previous
//
#include <hip/hip_runtime.h>
#include <hip/hip_bf16.h>
#include <math.h>

// Problem constants
#define BB 2
#define SS 2048
#define EE 1024
#define HH 16
#define HD 64
#define FFF 4096
#define MROWS (BB * SS)        // 4096
#define EPS_F 1.1920929e-7f
#define NQKV 1152              // 1024 q + 64 k + 64 v

typedef __hip_bfloat16 bf16;
typedef __attribute__((ext_vector_type(8))) short short8;
typedef __attribute__((ext_vector_type(4))) short short4v;
typedef __attribute__((ext_vector_type(4))) float floatx4;

typedef const __attribute__((address_space(1))) void* gas_t;
typedef __attribute__((address_space(3))) void* las_t;

// scheduling primitives for the 8-phase FFN kernel
#define BAR __builtin_amdgcn_s_barrier()
#define WLG do { asm volatile("s_waitcnt lgkmcnt(0)" ::: "memory"); \
                 __builtin_amdgcn_sched_barrier(0); } while (0)
#define VMC(N) asm volatile("s_waitcnt vmcnt(" #N ")" ::: "memory")

// ---------------------------------------------------------------------------
// RMSNorm: fp32 in, bf16 out. float4-vectorized (cols == 1024 == 256*4).
// ---------------------------------------------------------------------------
__global__ __launch_bounds__(256) void rmsnorm_kernel(const float* __restrict__ x,
                                                      const float* __restrict__ g,
                                                      bf16* __restrict__ out,
                                                      int cols) {
    int row = blockIdx.x, tid = threadIdx.x;
    const float4* xr = (const float4*)(x + (size_t)row * cols);
    float4 v = xr[tid];
    float ss = v.x * v.x + v.y * v.y + v.z * v.z + v.w * v.w;
    for (int off = 32; off > 0; off >>= 1) ss += __shfl_xor(ss, off, 64);
    __shared__ float red[4];
    int wave = tid >> 6;
    if ((tid & 63) == 0) red[wave] = ss;
    __syncthreads();
    float tot = red[0] + red[1] + red[2] + red[3];
    float rs = rsqrtf(tot / (float)cols + EPS_F);
    float4 gv = ((const float4*)g)[tid];
    short4v o;
    {
        bf16 b0 = __float2bfloat16(v.x * rs * gv.x);
        bf16 b1 = __float2bfloat16(v.y * rs * gv.y);
        bf16 b2 = __float2bfloat16(v.z * rs * gv.z);
        bf16 b3 = __float2bfloat16(v.w * rs * gv.w);
        o[0] = *(short*)&b0; o[1] = *(short*)&b1;
        o[2] = *(short*)&b2; o[3] = *(short*)&b3;
    }
    *(short4v*)(out + (size_t)row * cols + tid * 4) = o;
}

// ---------------------------------------------------------------------------
// 32x32 transpose+cast tile body (shared by the two fused weight-prep kernels)
// ---------------------------------------------------------------------------
__device__ __forceinline__ void transpose_tile32(const float* __restrict__ W,
                                                 bf16* __restrict__ Wt,
                                                 int K, int N, int bx, int by,
                                                 int tid, float (*t)[33]) {
    int n0 = bx * 32, k0 = by * 32;
    int tx = tid & 31, ty = tid >> 5;   // ty 0..7
#pragma unroll
    for (int i = 0; i < 4; ++i) {
        int kk = ty + i * 8;
        t[kk][tx] = W[(size_t)(k0 + kk) * N + n0 + tx];
    }
    __syncthreads();
#pragma unroll
    for (int i = 0; i < 4; ++i) {
        int nn = ty + i * 8;
        Wt[(size_t)(n0 + nn) * K + k0 + tx] = __float2bfloat16(t[tx][nn]);
    }
}

// ---------------------------------------------------------------------------
// Fused attention-side prep (1 launch):
//   wq/wk/wv/wo transposes + [bq|bk|bv] pack + RoPE cos/sin tables.
// Block ranges: [0,1024) wq | [1024,1088) wk | [1088,1152) wv |
//               [1152,2176) wo | [2176,2432) rope table | [2432,2437) pack.
// ---------------------------------------------------------------------------
__global__ __launch_bounds__(256) void prep_weights_kernel(
        const float* __restrict__ wq, const float* __restrict__ wk,
        const float* __restrict__ wv, const float* __restrict__ wo,
        const float* __restrict__ bq, const float* __restrict__ bk,
        const float* __restrict__ bv,
        bf16* __restrict__ wqkvT, bf16* __restrict__ woT,
        float* __restrict__ bqkv, float* __restrict__ ct, float* __restrict__ st) {
    __shared__ float t[32][33];
    int bid = blockIdx.x, tid = threadIdx.x;
    if (bid < 1024) {
        transpose_tile32(wq, wqkvT, EE, EE, bid & 31, bid >> 5, tid, t);
    } else if (bid < 1088) {
        int b2 = bid - 1024;
        transpose_tile32(wk, wqkvT + (size_t)1024 * EE, EE, HD, b2 & 1, b2 >> 1, tid, t);
    } else if (bid < 1152) {
        int b2 = bid - 1088;
        transpose_tile32(wv, wqkvT + (size_t)1088 * EE, EE, HD, b2 & 1, b2 >> 1, tid, t);
    } else if (bid < 2176) {
        int b2 = bid - 1152;
        transpose_tile32(wo, woT, EE, EE, b2 & 31, b2 >> 5, tid, t);
    } else if (bid < 2432) {
        int idx = (bid - 2176) * 256 + tid;       // SS*32 = 65536 entries
        int i = idx & 31, s = idx >> 5;
        float inv = powf(10000.0f, -(float)i / 32.0f);
        float ang = (float)s * inv;
        ct[idx] = cosf(ang);
        st[idx] = sinf(ang);
    } else {
        int tt = (bid - 2432) * 256 + tid;
        if (tt < NQKV) {
            float v;
            if (tt < 1024)      v = bq[tt];
            else if (tt < 1088) v = bk[tt - 1024];
            else                v = bv[tt - 1088];
            bqkv[tt] = v;
        }
    }
}

// ---------------------------------------------------------------------------
// Fused FFN weight prep (1 launch): wg/wu/wd transposes.
// [0,4096) wg | [4096,8192) wu | [8192,12288) wd.
// ---------------------------------------------------------------------------
__global__ __launch_bounds__(256) void ffn_weights_kernel(
        const float* __restrict__ wg, const float* __restrict__ wu,
        const float* __restrict__ wd,
        bf16* __restrict__ wgT, bf16* __restrict__ wuT, bf16* __restrict__ wdT) {
    __shared__ float t[32][33];
    int bid = blockIdx.x, tid = threadIdx.x;
    if (bid < 4096) {
        transpose_tile32(wg, wgT, EE, FFF, bid & 127, bid >> 7, tid, t);
    } else if (bid < 8192) {
        int b2 = bid - 4096;
        transpose_tile32(wu, wuT, EE, FFF, b2 & 127, b2 >> 7, tid, t);
    } else {
        int b2 = bid - 8192;
        transpose_tile32(wd, wdT, FFF, EE, b2 & 31, b2 >> 5, tid, t);
    }
}

// ---------------------------------------------------------------------------
// Fused QKV GEMM + RoPE epilogue. Round-9: double-buffered stage-early loop
// (T3 minimal 2-phase — same proven pattern as attn_mfma): stage(t+1) is
// issued BEFORE compute(t), one __syncthreads per K-tile; the implicit
// vmcnt(0) at the barrier then waits on loads that had the whole compute
// phase to land -> per-iter cost max(latency, compute) not latency+compute.
// LDS chunk-XOR swizzle kept (round-8, conflicts=0). Bit-identical numerics.
// ---------------------------------------------------------------------------
#define GK 64

__global__ __launch_bounds__(256) void gemm_qkv_kernel(
        const bf16* __restrict__ A, const bf16* __restrict__ Bt,
        const float* __restrict__ bias,
        const float* __restrict__ ct, const float* __restrict__ st,
        bf16* __restrict__ qout, bf16* __restrict__ kout,
        bf16* __restrict__ vout, int K) {
    __shared__ short As[2][128 * GK];
    __shared__ short Bs[2][128 * GK];
    int tid = threadIdx.x;
    int wave = tid >> 6, lane = tid & 63;
    int wm = (wave >> 1) * 64, wn = (wave & 1) * 64;
    int row0 = blockIdx.y * 128, col0 = blockIdx.x * 128;
    int lr = lane & 15, lq = lane >> 4;
    int rsw = lr & 7;                     // read-side swizzle key (row&7)

    int srow = wave * 32 + (lane >> 3);
    int scol = ((lane & 7) ^ (lane >> 3)) * 8;   // pre-swizzled source chunk
    const bf16* Abase = A + (size_t)(row0 + srow) * K + scol;
    const bf16* Bbase = Bt + (size_t)(col0 + srow) * K + scol;

    auto stage = [&](int bb, int k0) {
#pragma unroll
        for (int c = 0; c < 4; ++c) {
            __builtin_amdgcn_global_load_lds(
                (gas_t)(Abase + (size_t)(c * 8) * K + k0),
                (las_t)&As[bb][(wave * 32 + c * 8) * GK], 16, 0, 0);
            __builtin_amdgcn_global_load_lds(
                (gas_t)(Bbase + (size_t)(c * 8) * K + k0),
                (las_t)&Bs[bb][(wave * 32 + c * 8) * GK], 16, 0, 0);
        }
    };

    floatx4 acc[4][4];
#pragma unroll
    for (int mi = 0; mi < 4; ++mi)
#pragma unroll
        for (int ni = 0; ni < 4; ++ni)
            acc[mi][ni] = (floatx4){0.f, 0.f, 0.f, 0.f};

    stage(0, 0);
    __syncthreads();
    int cur = 0;
    for (int k0 = 0; k0 < K; k0 += GK) {
        if (k0 + GK < K) stage(cur ^ 1, k0 + GK);   // overlaps this compute
#pragma unroll
        for (int ks = 0; ks < GK; ks += 32) {
            int cswz = (((ks >> 3) + lq) ^ rsw) * 8;   // swizzled chunk offset
            short8 af[4], bfr[4];
#pragma unroll
            for (int mi = 0; mi < 4; ++mi)
                af[mi] = *(const short8*)&As[cur][(wm + mi * 16 + lr) * GK + cswz];
#pragma unroll
            for (int ni = 0; ni < 4; ++ni)
                bfr[ni] = *(const short8*)&Bs[cur][(wn + ni * 16 + lr) * GK + cswz];
#pragma unroll
            for (int mi = 0; mi < 4; ++mi)
#pragma unroll
                for (int ni = 0; ni < 4; ++ni)
                    acc[mi][ni] = __builtin_amdgcn_mfma_f32_16x16x32_bf16(
                        af[mi], bfr[ni], acc[mi][ni], 0, 0, 0);
        }
        __syncthreads();   // drains next-tile staging + all waves done with cur
        cur ^= 1;
    }

    int hcol = col0 + wn;                 // 64-aligned head-span base
    if (hcol < 1088) {                    // q (hcol<1024) or k (hcol==1024)
        bool isQ = hcol < 1024;
#pragma unroll
        for (int mi = 0; mi < 4; ++mi) {
#pragma unroll
            for (int ni = 0; ni < 2; ++ni) {
                int i = ni * 16 + lr;
                float b1 = bias[hcol + i];
                float b2 = bias[hcol + i + 32];
#pragma unroll
                for (int r = 0; r < 4; ++r) {
                    int gr = row0 + wm + mi * 16 + lq * 4 + r;
                    int s = gr & (SS - 1);
                    float c  = ct[s * 32 + i];
                    float sn = st[s * 32 + i];
                    float t1 = acc[mi][ni][r] + b1;
                    float t2 = acc[mi][ni + 2][r] + b2;
                    float o1 = t1 * c - t2 * sn;
                    float o2 = t1 * sn + t2 * c;
                    if (isQ) {
                        qout[(size_t)gr * 1024 + hcol + i]      = __float2bfloat16(o1 * 0.125f);
                        qout[(size_t)gr * 1024 + hcol + i + 32] = __float2bfloat16(o2 * 0.125f);
                    } else {
                        kout[(size_t)gr * 64 + i]      = __float2bfloat16(o1);
                        kout[(size_t)gr * 64 + i + 32] = __float2bfloat16(o2);
                    }
                }
            }
        }
    } else {                              // v: plain bias + cast
#pragma unroll
        for (int mi = 0; mi < 4; ++mi)
#pragma unroll
            for (int ni = 0; ni < 4; ++ni) {
                int vcol = ni * 16 + lr;
                float bv_ = bias[1088 + vcol];
#pragma unroll
                for (int r = 0; r < 4; ++r) {
                    int gr = row0 + wm + mi * 16 + lq * 4 + r;
                    vout[(size_t)gr * 64 + vcol] = __float2bfloat16(acc[mi][ni][r] + bv_);
                }
            }
    }
}

// ---------------------------------------------------------------------------
// GEMM 128x64 tiles (wo, wd): C = A@Bt^T + bias + aux.
// Round-8 fixed conflicts (0) + over-fetch (57MB ~ ideal); residual signature
// (MfmaUtil 20 / VALU 20 / HBM 15 / Occ 19 — nothing saturated) = latency-
// bound serial stage->drain->compute chain. Round-9: double-buffered
// stage-early loop (T3 minimal 2-phase, attn-proven). LDS 48KB (2 blocks/CU
// still fit). XCD swizzle + LDS swizzle kept. Bit-identical numerics.
// ---------------------------------------------------------------------------
__global__ __launch_bounds__(256) void gemm_n64_kernel(
        const bf16* __restrict__ A, const bf16* __restrict__ Bt,
        const float* __restrict__ bias, const float* __restrict__ aux,
        float* __restrict__ C, int M, int N, int K) {
    __shared__ short As[2][128 * GK];
    __shared__ short Bs[2][64 * GK];
    int tid = threadIdx.x;
    int wave = tid >> 6, lane = tid & 63;
    int wm = wave * 32;

    // XCD-aware remap of the (16 x 32) grid
    int nwg = gridDim.x * gridDim.y;                 // 512
    int id  = blockIdx.y * gridDim.x + blockIdx.x;
    int swz = (id & 7) * (nwg >> 3) + (id >> 3);
    int bx = swz % gridDim.x, by = swz / gridDim.x;
    int row0 = by * 128, col0 = bx * 64;

    int lr = lane & 15, lq = lane >> 4;
    int rsw = lr & 7;

    int srow = (lane >> 3);
    int scol = ((lane & 7) ^ (lane >> 3)) * 8;       // pre-swizzled source
    const bf16* Abase = A + (size_t)(row0 + wave * 32 + srow) * K + scol;
    const bf16* Bbase = Bt + (size_t)(col0 + wave * 16 + srow) * K + scol;

    auto stage = [&](int bb, int k0) {
#pragma unroll
        for (int c = 0; c < 4; ++c)
            __builtin_amdgcn_global_load_lds(
                (gas_t)(Abase + (size_t)(c * 8) * K + k0),
                (las_t)&As[bb][(wave * 32 + c * 8) * GK], 16, 0, 0);
#pragma unroll
        for (int c = 0; c < 2; ++c)
            __builtin_amdgcn_global_load_lds(
                (gas_t)(Bbase + (size_t)(c * 8) * K + k0),
                (las_t)&Bs[bb][(wave * 16 + c * 8) * GK], 16, 0, 0);
    };

    floatx4 acc[2][4];
#pragma unroll
    for (int mi = 0; mi < 2; ++mi)
#pragma unroll
        for (int ni = 0; ni < 4; ++ni)
            acc[mi][ni] = (floatx4){0.f, 0.f, 0.f, 0.f};

    stage(0, 0);
    __syncthreads();
    int cur = 0;
    for (int k0 = 0; k0 < K; k0 += GK) {
        if (k0 + GK < K) stage(cur ^ 1, k0 + GK);   // overlaps this compute
#pragma unroll
        for (int ks = 0; ks < GK; ks += 32) {
            int cswz = (((ks >> 3) + lq) ^ rsw) * 8;
            short8 af[2], bfr[4];
#pragma unroll
            for (int mi = 0; mi < 2; ++mi)
                af[mi] = *(const short8*)&As[cur][(wm + mi * 16 + lr) * GK + cswz];
#pragma unroll
            for (int ni = 0; ni < 4; ++ni)
                bfr[ni] = *(const short8*)&Bs[cur][(ni * 16 + lr) * GK + cswz];
#pragma unroll
            for (int mi = 0; mi < 2; ++mi)
#pragma unroll
                for (int ni = 0; ni < 4; ++ni)
                    acc[mi][ni] = __builtin_amdgcn_mfma_f32_16x16x32_bf16(
                        af[mi], bfr[ni], acc[mi][ni], 0, 0, 0);
        }
        __syncthreads();   // drains next-tile staging + all waves done with cur
        cur ^= 1;
    }

#pragma unroll
    for (int mi = 0; mi < 2; ++mi) {
#pragma unroll
        for (int ni = 0; ni < 4; ++ni) {
            int gc = col0 + ni * 16 + lr;
            float bv = bias[gc];
#pragma unroll
            for (int r = 0; r < 4; ++r) {
                int gr = row0 + wm + mi * 16 + lq * 4 + r;
                size_t idx = (size_t)gr * N + gc;
                C[idx] = acc[mi][ni][r] + bv + aux[idx];
            }
        }
    }
}

// ---------------------------------------------------------------------------
// Fused FFN GEMM, 8-phase schedule (T2+T3+T4+T5), swizzled + B-reg-reuse.
// Two row-half launches (instrumentation: keeps top-5 informative).
// ---------------------------------------------------------------------------
#define FFN_RD_A(KH, MH) \
    { const short* Ap = &Ab[buf][KH][0]; \
      af[0] = *(const short8*)&Ap[(wr * 128 + ((MH) * 4 + 0) * 16 + lr) * 32 + cs8]; \
      af[1] = *(const short8*)&Ap[(wr * 128 + ((MH) * 4 + 1) * 16 + lr) * 32 + cs8]; \
      af[2] = *(const short8*)&Ap[(wr * 128 + ((MH) * 4 + 2) * 16 + lr) * 32 + cs8]; \
      af[3] = *(const short8*)&Ap[(wr * 128 + ((MH) * 4 + 3) * 16 + lr) * 32 + cs8]; }

#define FFN_RD_B(KH) \
    { const short* Bp = &Bb[buf][KH][0]; \
      gf[0] = *(const short8*)&Bp[(wc * 32 + lr) * 32 + cs8]; \
      gf[1] = *(const short8*)&Bp[(wc * 32 + 16 + lr) * 32 + cs8]; \
      uf[0] = *(const short8*)&Bp[4096 + (wc * 32 + lr) * 32 + cs8]; \
      uf[1] = *(const short8*)&Bp[4096 + (wc * 32 + 16 + lr) * 32 + cs8]; }

#define FFN_MM(MH) \
    __builtin_amdgcn_s_setprio(1); \
    { _Pragma("unroll") for (int mi = 0; mi < 4; ++mi) { \
        ag[(MH) * 4 + mi][0] = __builtin_amdgcn_mfma_f32_16x16x32_bf16(af[mi], gf[0], ag[(MH) * 4 + mi][0], 0, 0, 0); \
        ag[(MH) * 4 + mi][1] = __builtin_amdgcn_mfma_f32_16x16x32_bf16(af[mi], gf[1], ag[(MH) * 4 + mi][1], 0, 0, 0); \
        au[(MH) * 4 + mi][0] = __builtin_amdgcn_mfma_f32_16x16x32_bf16(af[mi], uf[0], au[(MH) * 4 + mi][0], 0, 0, 0); \
        au[(MH) * 4 + mi][1] = __builtin_amdgcn_mfma_f32_16x16x32_bf16(af[mi], uf[1], au[(MH) * 4 + mi][1], 0, 0, 0); } } \
    __builtin_amdgcn_s_setprio(0);

__global__ __launch_bounds__(512, 2) void gemm_ffn_kernel(
        const bf16* __restrict__ A, const bf16* __restrict__ Bg,
        const bf16* __restrict__ Bu, const float* __restrict__ biasg,
        const float* __restrict__ biasu, bf16* __restrict__ C, int K, int rowoff) {
    __shared__ short Ab[2][2][8192];   // [buf][khalf][256 rows x 32 cols, swz]
    __shared__ short Bb[2][2][8192];   // [buf][khalf][G 128 | U 128, swz]

    const int tid = threadIdx.x;
    const int w = tid >> 6, lane = tid & 63;
    const int wr = w >> 2, wc = w & 3;           // 2M x 4N waves
    const int lr = lane & 15, quad = lane >> 4;
    const int row0 = (blockIdx.y + rowoff) * 256, col0 = blockIdx.x * 128;
    const int NT = K >> 6;                       // 16 K-tiles
    const int cs8 = (quad ^ ((lr >> 1) & 3)) * 8;   // swizzled read chunk

    const int sr = tid >> 2;                     // staging row 0..127
    const int scs = (((tid & 3) ^ ((tid >> 3) & 3))) * 8;

    auto stageA = [&](short* dst, int kcol) {
        __builtin_amdgcn_global_load_lds(
            (gas_t)(A + (size_t)(row0 + sr) * K + kcol + scs),
            (las_t)(dst + tid * 8), 16, 0, 0);
        __builtin_amdgcn_global_load_lds(
            (gas_t)(A + (size_t)(row0 + 128 + sr) * K + kcol + scs),
            (las_t)(dst + 4096 + tid * 8), 16, 0, 0);
    };
    auto stageB = [&](short* dst, int kcol) {
        __builtin_amdgcn_global_load_lds(
            (gas_t)(Bg + (size_t)(col0 + sr) * K + kcol + scs),
            (las_t)(dst + tid * 8), 16, 0, 0);
        __builtin_amdgcn_global_load_lds(
            (gas_t)(Bu + (size_t)(col0 + sr) * K + kcol + scs),
            (las_t)(dst + 4096 + tid * 8), 16, 0, 0);
    };

    floatx4 ag[8][2], au[8][2];
#pragma unroll
    for (int mi = 0; mi < 8; ++mi)
#pragma unroll
        for (int ni = 0; ni < 2; ++ni) {
            ag[mi][ni] = (floatx4){0.f, 0.f, 0.f, 0.f};
            au[mi][ni] = (floatx4){0.f, 0.f, 0.f, 0.f};
        }

    // prologue: 6 half-tiles; drain to 8 outstanding (t0A0,t0B0 landed)
    stageA(&Ab[0][0][0], 0);
    stageB(&Bb[0][0][0], 0);
    stageA(&Ab[0][1][0], 32);
    stageB(&Bb[0][1][0], 32);
    stageA(&Ab[1][0][0], 64);
    stageB(&Bb[1][0][0], 64);
    VMC(8);
    BAR;

    for (int k = 0; k < NT; ++k) {
        const int buf = k & 1;
        short8 gf[2], uf[2];
        {   // phase 1: kh0, mh0 | read af + gf/uf(kh0) | stage tile k+1 A-k1
            short8 af[4];
            FFN_RD_A(0, 0)
            FFN_RD_B(0)
            if (k + 1 < NT) stageA(&Ab[buf ^ 1][1][0], (k + 1) * 64 + 32);
            BAR; WLG;
            FFN_MM(0)
            BAR;
        }
        {   // phase 2: kh0, mh1 | af only (gf/uf in regs) | stage k+1 B-k1
            short8 af[4];
            FFN_RD_A(0, 1)
            if (k + 1 < NT) stageB(&Bb[buf ^ 1][1][0], (k + 1) * 64 + 32);
            BAR; WLG;
            FFN_MM(1)
            if (k < NT - 1) { VMC(8); } else { VMC(0); }
            BAR;
        }
        {   // phase 3: kh1, mh0 | read af + gf/uf(kh1) | stage k+2 A-k0
            short8 af[4];
            FFN_RD_A(1, 0)
            FFN_RD_B(1)
            if (k + 2 < NT) stageA(&Ab[buf][0][0], (k + 2) * 64);
            BAR; WLG;
            FFN_MM(0)
            BAR;
        }
        {   // phase 4: kh1, mh1 | af only | stage k+2 B-k0
            short8 af[4];
            FFN_RD_A(1, 1)
            if (k + 2 < NT) stageB(&Bb[buf][0][0], (k + 2) * 64);
            BAR; WLG;
            FFN_MM(1)
            if (k < NT - 2) { VMC(8); } else if (k == NT - 2) { VMC(4); }
            BAR;
        }
    }

#pragma unroll
    for (int mi = 0; mi < 8; ++mi) {
#pragma unroll
        for (int ni = 0; ni < 2; ++ni) {
            int gc = col0 + wc * 32 + ni * 16 + lr;
            float bg_ = biasg[gc], bu_ = biasu[gc];
#pragma unroll
            for (int r = 0; r < 4; ++r) {
                int gr = row0 + wr * 128 + mi * 16 + quad * 4 + r;
                float g = ag[mi][ni][r] + bg_;
                float u = au[mi][ni][r] + bu_;
                float v = 0.5f * g * (1.0f + erff(g * 0.70710678118654752f)) * u;
                C[(size_t)gr * FFF + gc] = __float2bfloat16(v);
            }
        }
    }
}

// ---------------------------------------------------------------------------
// prep_v: vb bf16 (MROWS,64) -> vtb bf16 (BB,64,SS) transposed per batch.
// ---------------------------------------------------------------------------
__global__ __launch_bounds__(256) void prep_v_kernel(const bf16* __restrict__ vb,
                                                     bf16* __restrict__ vtb) {
    __shared__ short t[64][65];
    int s0 = blockIdx.x * 64, b = blockIdx.y;
    int tid = threadIdx.x;
    const short* vs = (const short*)vb;
    short* vd = (short*)vtb;
    for (int i = tid; i < 4096; i += 256) {
        int s = i >> 6, d = i & 63;
        t[d][s] = vs[((size_t)(b * SS + s0 + s)) * 64 + d];
    }
    __syncthreads();
    for (int i = tid; i < 4096; i += 256) {
        int d = i >> 6, sl = i & 63;
        vd[((size_t)(b * 64 + d)) * SS + s0 + sl] = t[d][sl];
    }
}

// ---------------------------------------------------------------------------
// MFMA flash attention v6: fixed-shift softmax + k-split-2 (unchanged math)
// with LDS-staged, double-buffered K/V tiles. XOR-swizzled (both-sides).
// ---------------------------------------------------------------------------
#define PST 68
#define SM_SHIFT 6.0f

__global__ __launch_bounds__(256, 3) void attn_mfma_kernel(
        const bf16* __restrict__ q, const bf16* __restrict__ kb,
        const bf16* __restrict__ vt,
        float* __restrict__ O0p, float* __restrict__ O1p,
        float* __restrict__ l0p, float* __restrict__ l1p) {
    __shared__ short Kb_s[2][64 * 64];
    __shared__ short Vb_s[2][64 * 64];
    __shared__ short Ps[4][16 * PST];

    int h = blockIdx.y, b = blockIdx.z;
    int px = blockIdx.x >> 1, half = blockIdx.x & 1;
    int tid = threadIdx.x, w = tid >> 6, lane = tid & 63;
    int lr = lane & 15, quad = lane >> 4;
    int rsw = lane & 7;                 // read-side swizzle: row&7 == lr&7

    float* __restrict__ Op = half ? O1p : O0p;
    float* __restrict__ lp = half ? l1p : l0p;

    const bf16* kbB = kb + (size_t)b * SS * 64;
    const bf16* vtB = vt + (size_t)b * 64 * SS;

    int st_sub = lane >> 3;
    int st_col = ((lane & 7) ^ st_sub) << 3;      // element offset within row

    auto stage_tile = [&](int nxt, int j0s) {
#pragma unroll
        for (int i = 0; i < 2; ++i) {
            int rr = i * 32 + w * 8 + st_sub;
            __builtin_amdgcn_global_load_lds(
                (gas_t)(kbB + (size_t)(j0s + rr) * 64 + st_col),
                (las_t)&Kb_s[nxt][(i * 256 + w * 64) * 8], 16, 0, 0);
            __builtin_amdgcn_global_load_lds(
                (gas_t)(vtB + (size_t)rr * SS + j0s + st_col),
                (las_t)&Vb_s[nxt][(i * 256 + w * 64) * 8], 16, 0, 0);
        }
    };

    for (int pass = 0; pass < 2; ++pass) {
        int qt = (pass == 0) ? px : (SS / 64 - 1 - px);
        int q0 = qt * 64;

        const bf16* qrow = q + ((size_t)(b * SS + q0 + w * 16 + lr)) * (HH * HD) + h * HD;
        short8 qf0 = *(const short8*)(qrow + quad * 8);
        short8 qf1 = *(const short8*)(qrow + 32 + quad * 8);

        int n  = qt + 1;            // total k-tiles for this q-tile
        int n0 = (n + 1) >> 1;      // half 0 takes [0,n0), half 1 takes [n0,n)
        int tlo = half ? n0 : 0;
        int thi = half ? n  : n0;

        floatx4 O[4];
#pragma unroll
        for (int ni = 0; ni < 4; ++ni) O[ni] = (floatx4){0.f, 0.f, 0.f, 0.f};
        float lrow[4] = {0.f, 0.f, 0.f, 0.f};

        int cur = 0;
        if (tlo < thi) stage_tile(0, tlo * 64);
        __syncthreads();

        for (int t = tlo; t < thi; ++t) {
            // stage next tile into the other buffer (overlaps this compute)
            if (t + 1 < thi) stage_tile(cur ^ 1, (t + 1) * 64);

            int j0 = t * 64;

            // S = Q @ K^T   (K fragments from swizzled LDS)
            floatx4 S[4];
#pragma unroll
            for (int ni = 0; ni < 4; ++ni) S[ni] = (floatx4){0.f, 0.f, 0.f, 0.f};
#pragma unroll
            for (int ni = 0; ni < 4; ++ni) {
                const short* Kc = &Kb_s[cur][(ni * 16 + lr) * 64];
                short8 b0 = *(const short8*)&Kc[(quad ^ rsw) * 8];
                short8 b1 = *(const short8*)&Kc[((quad ^ rsw) ^ 4) * 8];
                S[ni] = __builtin_amdgcn_mfma_f32_16x16x32_bf16(qf0, b0, S[ni], 0, 0, 0);
                S[ni] = __builtin_amdgcn_mfma_f32_16x16x32_bf16(qf1, b1, S[ni], 0, 0, 0);
            }

            // V fragments (swizzled LDS), issued early to overlap exp + pack
            short8 vf[8];
#pragma unroll
            for (int ni = 0; ni < 4; ++ni) {
                const short* Vc = &Vb_s[cur][(ni * 16 + lr) * 64];
                vf[2 * ni]     = *(const short8*)&Vc[(quad ^ rsw) * 8];
                vf[2 * ni + 1] = *(const short8*)&Vc[((quad ^ rsw) ^ 4) * 8];
            }

            // causal mask on diagonal tile
            if (t == qt) {
                int rowg = q0 + w * 16 + quad * 4;
#pragma unroll
                for (int ni = 0; ni < 4; ++ni) {
                    int colg = j0 + ni * 16 + lr;
#pragma unroll
                    for (int r = 0; r < 4; ++r)
                        if (colg > rowg + r) S[ni][r] = -3.0e38f;
                }
            }

            // fixed-shift exp; accumulate per-lane row sums (no cross-lane ops)
#pragma unroll
            for (int ni = 0; ni < 4; ++ni)
#pragma unroll
                for (int r = 0; r < 4; ++r)
                    S[ni][r] = __expf(S[ni][r] - SM_SHIFT);
#pragma unroll
            for (int r = 0; r < 4; ++r)
                lrow[r] += S[0][r] + S[1][r] + S[2][r] + S[3][r];

            // pack P (bf16) to wave-private LDS in C-layout
#pragma unroll
            for (int ni = 0; ni < 4; ++ni)
#pragma unroll
                for (int r = 0; r < 4; ++r) {
                    bf16 pb = __float2bfloat16(S[ni][r]);
                    Ps[w][(quad * 4 + r) * PST + ni * 16 + lr] = *(short*)&pb;
                }
            short4v a0 = *(const short4v*)&Ps[w][lr * PST + quad * 8];
            short4v a1 = *(const short4v*)&Ps[w][lr * PST + quad * 8 + 4];
            short4v a2 = *(const short4v*)&Ps[w][lr * PST + 32 + quad * 8];
            short4v a3 = *(const short4v*)&Ps[w][lr * PST + 32 + quad * 8 + 4];
            short8 p0 = __builtin_shufflevector(a0, a1, 0, 1, 2, 3, 4, 5, 6, 7);
            short8 p1 = __builtin_shufflevector(a2, a3, 0, 1, 2, 3, 4, 5, 6, 7);

            // O += P @ V
#pragma unroll
            for (int ni = 0; ni < 4; ++ni) {
                O[ni] = __builtin_amdgcn_mfma_f32_16x16x32_bf16(p0, vf[2 * ni], O[ni], 0, 0, 0);
                O[ni] = __builtin_amdgcn_mfma_f32_16x16x32_bf16(p1, vf[2 * ni + 1], O[ni], 0, 0, 0);
            }

            // drains next-tile staging + ensures all waves done with cur
            __syncthreads();
            cur ^= 1;
        }

        // deferred row-sum reduction over the quad's 16 lanes (once per pass)
#pragma unroll
        for (int r = 0; r < 4; ++r) {
            float l = lrow[r];
            for (int off = 1; off < 16; off <<= 1) l += __shfl_xor(l, off, 64);
            lrow[r] = l;
        }

        // write unnormalized partials (zeros when this half's range is empty)
#pragma unroll
        for (int ni = 0; ni < 4; ++ni) {
            int gc = h * 64 + ni * 16 + lr;
#pragma unroll
            for (int r = 0; r < 4; ++r) {
                int gr = b * SS + q0 + w * 16 + quad * 4 + r;
                Op[(size_t)gr * (HH * HD) + gc] = O[ni][r];
            }
        }
        if (lr == 0) {
#pragma unroll
            for (int r = 0; r < 4; ++r) {
                int gr = b * SS + q0 + w * 16 + quad * 4 + r;
                lp[(size_t)gr * HH + h] = lrow[r];
            }
        }
    }
}

// ---------------------------------------------------------------------------
// Combine the two key-range halves: ao = (O0+O1)/(l0+l1), bf16 out.
// ---------------------------------------------------------------------------
__global__ __launch_bounds__(256) void attn_combine_kernel(
        const float* __restrict__ O0p, const float* __restrict__ O1p,
        const float* __restrict__ l0p, const float* __restrict__ l1p,
        bf16* __restrict__ o) {
    int idx = blockIdx.x * 256 + threadIdx.x;   // < MROWS*1024/4
    int d4  = idx & 15;
    int hh  = (idx >> 4) & 15;
    int row = idx >> 8;
    float l = l0p[row * HH + hh] + l1p[row * HH + hh];
    float inv = 1.0f / l;
    size_t base = (size_t)row * (HH * HD) + hh * 64 + d4 * 4;
    float4 a = *(const float4*)(O0p + base);
    float4 c = *(const float4*)(O1p + base);
    short4v o4;
    {
        bf16 v0 = __float2bfloat16((a.x + c.x) * inv);
        bf16 v1 = __float2bfloat16((a.y + c.y) * inv);
        bf16 v2 = __float2bfloat16((a.z + c.z) * inv);
        bf16 v3 = __float2bfloat16((a.w + c.w) * inv);
        o4[0] = *(short*)&v0; o4[1] = *(short*)&v1;
        o4[2] = *(short*)&v2; o4[3] = *(short*)&v3;
    }
    *(short4v*)(o + base) = o4;
}

// ---------------------------------------------------------------------------
// Launch (12 dispatches). Workspace (byte offsets, high-water 87 MB):
//   qbf @0 (8 MB, dead after attn; wgT reuses @0) | wuT @8M
//   x2 @16M (fp32 16 MB, written at wo; Opart0 borrows @16M during attn)
//   h1b/h2b @32M (8 MB) | vb @40M (bf16 0.5 MB)
//   ao @42M (8 MB, dead after wo; wdT reuses)
//   gg @50M (32 MB; pre-FFN its body hosts kbf @50M, vtb @50.5M, Opart1 @51M,
//            lparts @67M, rope tables @70M — all dead before gg is written)
//   wqkvT @82M (2.25 MB) | bqkv @84.5M | woT @85M (2 MB)
// ---------------------------------------------------------------------------
#define MB (1024ull * 1024ull)

extern "C" void kernel_launch(void* const* d_in, const int* in_sizes, int n_in,
                              void* d_out, int out_size, void* d_ws, size_t ws_size,
                              hipStream_t stream) {
    const float* x  = (const float*)d_in[0];
    const float* wq = (const float*)d_in[1];
    const float* bq = (const float*)d_in[2];
    const float* wk = (const float*)d_in[3];
    const float* bk = (const float*)d_in[4];
    const float* wv = (const float*)d_in[5];
    const float* bv = (const float*)d_in[6];
    const float* wo = (const float*)d_in[7];
    const float* bo = (const float*)d_in[8];
    const float* wg = (const float*)d_in[9];
    const float* bg = (const float*)d_in[10];
    const float* wu = (const float*)d_in[11];
    const float* bu = (const float*)d_in[12];
    const float* wd = (const float*)d_in[13];
    const float* bd = (const float*)d_in[14];
    const float* g1 = (const float*)d_in[15];
    const float* g2 = (const float*)d_in[16];
    float* out = (float*)d_out;

    char* ws = (char*)d_ws;
    bf16*  qbf   = (bf16*)(ws);
    bf16*  wuT   = (bf16*)(ws + 8 * MB);
    float* x2    = (float*)(ws + 16 * MB);
    bf16*  h1b   = (bf16*)(ws + 32 * MB);
    bf16*  vb    = (bf16*)(ws + 40 * MB);
    bf16*  ao    = (bf16*)(ws + 42 * MB);
    bf16*  gg    = (bf16*)(ws + 50 * MB);
    bf16*  kbf   = (bf16*)(ws + 50 * MB);              // over gg head (dead by FFN)
    bf16*  vtb   = (bf16*)(ws + 50 * MB + 512 * 1024);
    float* Opart0 = (float*)(ws + 16 * MB);            // over x2 (attn phase)
    float* Opart1 = (float*)(ws + 51 * MB);            // inside gg body
    float* lpart0 = (float*)(ws + 67 * MB);
    float* lpart1 = (float*)(ws + 67 * MB + 256 * 1024);
    float* ctab   = (float*)(ws + 70 * MB);
    float* stab   = (float*)(ws + 70 * MB + 256 * 1024);
    bf16*  wqkvT = (bf16*)(ws + 82 * MB);
    float* bqkv  = (float*)(ws + 84 * MB + 512 * 1024);
    bf16*  woT   = (bf16*)(ws + 85 * MB);
    bf16*  wgT   = (bf16*)(ws);                        // over qbf (dead after attn)
    bf16*  wdT   = (bf16*)(ws + 42 * MB);              // over ao (dead after wo GEMM)
    bf16*  h2b   = h1b;

    // 1. fused attention-side weight prep
    prep_weights_kernel<<<2437, 256, 0, stream>>>(
        wq, wk, wv, wo, bq, bk, bv, wqkvT, woT, bqkv, ctab, stab);

    // 2. h1 = rmsnorm(x, g1)
    rmsnorm_kernel<<<MROWS, 256, 0, stream>>>(x, g1, h1b, EE);

    // 3. fused QKV projection + RoPE epilogue -> qbf, kbf, vb  [dbuf staged]
    gemm_qkv_kernel<<<dim3(NQKV / 128, MROWS / 128), 256, 0, stream>>>(
        h1b, wqkvT, bqkv, ctab, stab, qbf, kbf, vb, EE);

    // 4. v transpose -> vtb
    prep_v_kernel<<<dim3(SS / 64, BB), 256, 0, stream>>>(vb, vtb);

    // 5. attention partials (k-split x2) + combine -> ao [bf16]
    attn_mfma_kernel<<<dim3(2 * SS / 128, HH, BB), 256, 0, stream>>>(
        qbf, kbf, vtb, Opart0, Opart1, lpart0, lpart1);
    attn_combine_kernel<<<(MROWS * HH * HD / 4) / 256, 256, 0, stream>>>(
        Opart0, Opart1, lpart0, lpart1, ao);

    // 6. x2 = ao @ wo + bo + x  [dbuf staged + LDS swizzle + XCD swizzle]
    gemm_n64_kernel<<<dim3(EE / 64, MROWS / 128), 256, 0, stream>>>(
        ao, woT, bo, x, x2, MROWS, EE, EE);

    // 7. h2 = rmsnorm(x2, g2)
    rmsnorm_kernel<<<MROWS, 256, 0, stream>>>(x2, g2, h2b, EE);

    // 8. fused FFN weight prep (qbf + ao now dead)
    ffn_weights_kernel<<<12288, 256, 0, stream>>>(wg, wu, wd, wgT, wuT, wdT);

    // 9. gg = gelu(h2@wg+bg) * (h2@wu+bu) — two row-half launches
    gemm_ffn_kernel<<<dim3(FFF / 128, MROWS / 512), 512, 0, stream>>>(
        h2b, wgT, wuT, bg, bu, gg, EE, 0);
    gemm_ffn_kernel<<<dim3(FFF / 128, MROWS / 512), 512, 0, stream>>>(
        h2b, wgT, wuT, bg, bu, gg, EE, MROWS / 512);

    // 10. out = gg @ wd + bd + x2  [dbuf staged + LDS swizzle + XCD swizzle]
    gemm_n64_kernel<<<dim3(EE / 64, MROWS / 128), 256, 0, stream>>>(
        gg, wdT, bd, x2, out, MROWS, EE, FFF);
}